// Round 14
// baseline (534.204 us; speedup 1.0000x reference)
//
#include <hip/hip_runtime.h>

#define EPS 1e-5f

#define B_   4096
#define NG_  1440
#define DR_  222
#define D_   50
#define NA_  64
#define LG_  3
#define L1_  713
#define C1_  10
#define K1_  15
#define L2_  350
#define C2_  5
#define LP_  70
#define LO_  32
#define CAT_ 210
#define M_   100
#define LM1_ 46
#define PM1_ 15
#define LM2_ 3

#define X1ST_ 360     // x1E/x1O row stride (>= 357)
#define NFUSE_ 666    // fuse blocks (111 drug-pairs x 6 gene-chunks)

// ---------------- Kernel 1: fused {P = sim @ clip(fw)} + {GNN} ----------------
// blocks [0,666): fuse; blocks [666, 888): gnn (independent work, co-resident)
__global__ void k_fusegnn(
    const float* __restrict__ fw, const float* __restrict__ sim,
    float* __restrict__ P,
    const float* __restrict__ embed, const float* __restrict__ gW,
    const float* __restrict__ gb, const int* __restrict__ fp,
    const float* __restrict__ adj, float* __restrict__ compound)
{
  const int bx = blockIdx.x;
  const int tid = threadIdx.x;
  __shared__ float s0[DR_], s1[DR_];
  __shared__ __align__(16) float WT[D_ * 52];
  __shared__ __align__(16) float hsl[NA_ * 52];
  __shared__ float xsl[NA_ * 53];
  __shared__ float bl[D_];
  __shared__ int fps[NA_];

  if (bx < NFUSE_) {
    const int d0 = (bx / 6) * 2;
    const int g = (bx % 6) * 256 + tid;
    for (int r = tid; r < DR_; r += 256) {
      s0[r] = sim[d0 * DR_ + r];
      s1[r] = sim[(d0 + 1) * DR_ + r];
    }
    __syncthreads();
    if (g >= NG_) return;
    float a0 = 0.f, a1 = 0.f;
#pragma unroll 6
    for (int r = 0; r < DR_; ++r) {
      float w = fw[r * NG_ + g];
      w = fminf(fmaxf(w, 0.f), 1.f);
      a0 += s0[r] * w;
      a1 += s1[r] * w;
    }
    P[d0 * NG_ + g] = a0;
    P[(d0 + 1) * NG_ + g] = a1;
    return;
  }

  // ---- GNN branch ----
  const int d = bx - NFUSE_;
  const int wid = tid >> 6, lane = tid & 63;

  if (tid < NA_) fps[tid] = fp[d * NA_ + tid];
  if (wid == 0) { hsl[lane * 52 + 50] = 0.f; hsl[lane * 52 + 51] = 0.f; }
  __syncthreads();

  float xs[52];
  const float* erow = embed + (size_t)fps[lane] * D_;
#pragma unroll
  for (int j = 0; j < D_; ++j) xs[j] = erow[j];
  xs[50] = 0.f; xs[51] = 0.f;
  float Ar[NA_];
  const float* arow = adj + (size_t)d * NA_ * NA_ + lane * NA_;
#pragma unroll
  for (int j = 0; j < NA_; ++j) Ar[j] = arow[j];

  const int e0 = (wid < 2) ? wid * 13 : 26 + (wid - 2) * 12;
  const int ecnt = (wid < 2) ? 13 : 12;

  for (int layer = 0; layer < LG_; ++layer) {
    const float* Wg = gW + layer * D_ * D_;
    for (int i = tid; i < D_ * 52; i += 256) {
      int e = i / 52, dd = i - e * 52;
      WT[i] = (dd < D_) ? Wg[dd * D_ + e] : 0.f;
    }
    if (tid < D_) bl[tid] = gb[layer * D_ + tid];
    __syncthreads();

    for (int ei = 0; ei < ecnt; ++ei) {
      int e = e0 + ei;
      float c0 = bl[e], c1 = 0.f, c2 = 0.f, c3 = 0.f;
#pragma unroll
      for (int c = 0; c < 13; ++c) {
        float4 wv = *(const float4*)&WT[e * 52 + 4 * c];
        c0 += xs[4 * c + 0] * wv.x;
        c1 += xs[4 * c + 1] * wv.y;
        c2 += xs[4 * c + 2] * wv.z;
        c3 += xs[4 * c + 3] * wv.w;
      }
      hsl[lane * 52 + e] = fmaxf((c0 + c1) + (c2 + c3), 0.f);
    }
    __syncthreads();

    for (int c = wid; c < 13; c += 4) {
      float a0 = 0.f, a1 = 0.f, a2 = 0.f, a3 = 0.f;
#pragma unroll
      for (int m = 0; m < NA_; ++m) {
        float4 hv = *(const float4*)&hsl[m * 52 + 4 * c];
        float am = Ar[m];
        a0 += am * hv.x; a1 += am * hv.y; a2 += am * hv.z; a3 += am * hv.w;
      }
      int dd = 4 * c;
      xsl[lane * 53 + dd + 0] = xs[dd + 0] + a0;
      xsl[lane * 53 + dd + 1] = xs[dd + 1] + a1;
      if (dd + 2 < D_) {
        xsl[lane * 53 + dd + 2] = xs[dd + 2] + a2;
        xsl[lane * 53 + dd + 3] = xs[dd + 3] + a3;
      }
    }
    __syncthreads();
#pragma unroll
    for (int j = 0; j < D_; ++j) xs[j] = xsl[lane * 53 + j];
    __syncthreads();
  }

  if (wid == 0 && lane < D_) {
    float s = 0.f;
    for (int n = 0; n < NA_; ++n) s += xsl[n * 53 + lane];
    compound[d * D_ + lane] = s * (1.f / NA_);
  }
}

// ---------------- Kernel 2: com (register-direct) + comg store + conv1 stats ----------------
__global__ __launch_bounds__(384, 4) void k_conv1(
    const float* __restrict__ rma, const float* __restrict__ varr,
    const int* __restrict__ did, const float* __restrict__ P,
    const float* __restrict__ w1g, const float* __restrict__ b1g,
    float* __restrict__ comg, float* __restrict__ part1)
{
  const int b = blockIdx.x, tid = threadIdx.x;
  const int wid = tid >> 6;
  __shared__ float red[6][C1_ * 2];
  const int dd = did[b];
  const float* rb = rma  + (size_t)b * NG_ + 4 * tid;
  const float* vb = varr + (size_t)b * NG_ + 4 * tid;
  const float* pp = P    + (size_t)dd * NG_ + 4 * tid;

  float s1[C1_], s2[C1_];
#pragma unroll
  for (int c = 0; c < C1_; ++c) { s1[c] = 0.f; s2[c] = 0.f; }

  if (tid < 357) {
    float4 r0 = *(const float4*)(rb + 0),  r1 = *(const float4*)(rb + 4);
    float4 r2 = *(const float4*)(rb + 8),  r3 = *(const float4*)(rb + 12);
    float4 v0 = *(const float4*)(vb + 0),  v1 = *(const float4*)(vb + 4);
    float4 v2 = *(const float4*)(vb + 8),  v3 = *(const float4*)(vb + 12);
    float4 p0 = *(const float4*)(pp + 0),  p1 = *(const float4*)(pp + 4);
    float4 p2 = *(const float4*)(pp + 8),  p3 = *(const float4*)(pp + 12);
    const bool two = (tid < 356);
    float wE[9], wO[8];
    wE[0] = r0.x + p0.x * v0.x;  wO[0] = r0.y + p0.y * v0.y;
    wE[1] = r0.z + p0.z * v0.z;  wO[1] = r0.w + p0.w * v0.w;
    wE[2] = r1.x + p1.x * v1.x;  wO[2] = r1.y + p1.y * v1.y;
    wE[3] = r1.z + p1.z * v1.z;  wO[3] = r1.w + p1.w * v1.w;
    wE[4] = r2.x + p2.x * v2.x;  wO[4] = r2.y + p2.y * v2.y;
    wE[5] = r2.z + p2.z * v2.z;  wO[5] = r2.w + p2.w * v2.w;
    wE[6] = r3.x + p3.x * v3.x;  wO[6] = r3.y + p3.y * v3.y;
    wE[7] = r3.z + p3.z * v3.z;  wO[7] = r3.w + p3.w * v3.w;
    wE[8] = two ? (rb[16] + pp[16] * vb[16]) : 0.f;
    *(float4*)&comg[(size_t)b * NG_ + 4 * tid] =
        make_float4(wE[0], wO[0], wE[1], wO[1]);
#pragma unroll
    for (int c = 0; c < C1_; ++c) {
      float a0 = b1g[c], a1 = a0;
#pragma unroll
      for (int m = 0; m < 8; ++m) {
        float w = w1g[c * K1_ + 2 * m];
        a0 += w * wE[m]; a1 += w * wE[m + 1];
      }
#pragma unroll
      for (int m = 0; m < 7; ++m) {
        float w = w1g[c * K1_ + 2 * m + 1];
        a0 += w * wO[m]; a1 += w * wO[m + 1];
      }
      s1[c] = a0; s2[c] = a0 * a0;
      if (two) { s1[c] += a1; s2[c] += a1 * a1; }
    }
  } else if (tid < 360) {
    float4 r0 = *(const float4*)(rb);
    float4 v0 = *(const float4*)(vb);
    float4 p0 = *(const float4*)(pp);
    *(float4*)&comg[(size_t)b * NG_ + 4 * tid] =
        make_float4(r0.x + p0.x * v0.x, r0.y + p0.y * v0.y,
                    r0.z + p0.z * v0.z, r0.w + p0.w * v0.w);
  }

#pragma unroll
  for (int c = 0; c < C1_; ++c) {
#pragma unroll
    for (int off = 32; off > 0; off >>= 1) {
      s1[c] += __shfl_down(s1[c], off, 64);
      s2[c] += __shfl_down(s2[c], off, 64);
    }
  }
  if ((tid & 63) == 0) {
#pragma unroll
    for (int c = 0; c < C1_; ++c) {
      red[wid][c * 2 + 0] = s1[c];
      red[wid][c * 2 + 1] = s2[c];
    }
  }
  __syncthreads();
  if (tid < C1_ * 2) {
    float S = 0.f;
#pragma unroll
    for (int w = 0; w < 6; ++w) S += red[w][tid];
    part1[b * (C1_ * 2) + tid] = S;   // (b*C1 + c)*2 + s
  }
}

// ---------------- BN finalize ----------------
__global__ __launch_bounds__(256) void k_bnfin(
    const float* __restrict__ part, int nblk, int C, float N,
    const float* __restrict__ g, const float* __restrict__ bta,
    float* __restrict__ ac)
{
  const int c = blockIdx.x, tid = threadIdx.x;
  float s1 = 0.f, s2 = 0.f;
  for (int j = tid; j < nblk; j += 256) {
    s1 += part[(j * C + c) * 2 + 0];
    s2 += part[(j * C + c) * 2 + 1];
  }
#pragma unroll
  for (int off = 32; off > 0; off >>= 1) {
    s1 += __shfl_down(s1, off, 64);
    s2 += __shfl_down(s2, off, 64);
  }
  __shared__ float r1[4], r2[4];
  int w = tid >> 6;
  if ((tid & 63) == 0) { r1[w] = s1; r2[w] = s2; }
  __syncthreads();
  if (tid == 0) {
    float S1 = r1[0] + r1[1] + r1[2] + r1[3];
    float S2 = r2[0] + r2[1] + r2[2] + r2[3];
    float mean = S1 / N;
    float v = S2 / N - mean * mean;
    float a = g[c] * rsqrtf(v + EPS);
    ac[c] = a;
    ac[C + c] = bta[c] - mean * a;
  }
}

// ---------------- Kernel 4: channel-split half-LDS double-pass; reg-cached windows; b64 phase-B reads ----------------
__global__ __launch_bounds__(192, 6) void k_conv2(
    const float* __restrict__ comg, const float* __restrict__ w1g,
    const float* __restrict__ b1g, const float* __restrict__ ac1,
    const float* __restrict__ w2g, const float* __restrict__ b2g,
    float* __restrict__ x2g, float* __restrict__ part2)
{
  const int b = blockIdx.x, tid = threadIdx.x;
  const int wid = tid >> 6;                 // 0..2
  __shared__ __align__(8) float x1E[5 * X1ST_], x1O[5 * X1ST_];
  __shared__ float red[3][C2_ * 2];

  // Load both j-iterations' windows ONCE into registers (reused by both g passes)
  const int j1 = tid + 192;
  const bool act0 = true;               // j0 = tid < 192 < 357 always
  const bool act1 = (j1 < 357);         // tid < 165
  const bool two0 = (tid < 356);        // always true for tid<192
  const bool two1 = (j1 < 356);         // tid < 164
  float wEa[9], wOa[8], wEb[9], wOb[8];
  {
    const float* base = comg + (size_t)b * NG_ + 4 * tid;
    float4 v0 = *(const float4*)(base + 0);
    float4 v1 = *(const float4*)(base + 4);
    float4 v2 = *(const float4*)(base + 8);
    float4 v3 = *(const float4*)(base + 12);
    wEa[0] = v0.x; wEa[1] = v0.z; wEa[2] = v1.x; wEa[3] = v1.z;
    wEa[4] = v2.x; wEa[5] = v2.z; wEa[6] = v3.x; wEa[7] = v3.z;
    wEa[8] = base[16];
    wOa[0] = v0.y; wOa[1] = v0.w; wOa[2] = v1.y; wOa[3] = v1.w;
    wOa[4] = v2.y; wOa[5] = v2.w; wOa[6] = v3.y; wOa[7] = v3.w;
  }
  if (act1) {
    const float* base = comg + (size_t)b * NG_ + 4 * j1;
    float4 v0 = *(const float4*)(base + 0);
    float4 v1 = *(const float4*)(base + 4);
    float4 v2 = *(const float4*)(base + 8);
    float4 v3 = *(const float4*)(base + 12);
    wEb[0] = v0.x; wEb[1] = v0.z; wEb[2] = v1.x; wEb[3] = v1.z;
    wEb[4] = v2.x; wEb[5] = v2.z; wEb[6] = v3.x; wEb[7] = v3.z;
    wEb[8] = two1 ? base[16] : 0.f;
    wOb[0] = v0.y; wOb[1] = v0.w; wOb[2] = v1.y; wOb[3] = v1.w;
    wOb[4] = v2.y; wOb[5] = v2.w; wOb[6] = v3.y; wOb[7] = v3.w;
  }

  float A0[C2_], A1[C2_];
#pragma unroll
  for (int co = 0; co < C2_; ++co) { A0[co] = 0.f; A1[co] = 0.f; }

#pragma unroll 1
  for (int g = 0; g < 2; ++g) {
    if (g) __syncthreads();   // previous phase B done before overwriting x1
    // Phase A: conv1+BN1+relu for channels g*5..g*5+4, from cached windows
#pragma unroll 1
    for (int cl = 0; cl < 5; ++cl) {
      const int c = g * 5 + cl;
      const float bc = b1g[c];
      const float sc = ac1[c], sh = ac1[C1_ + c];
      // iter 0: j = tid
      {
        float a0 = bc, a1 = bc;
#pragma unroll
        for (int m = 0; m < 8; ++m) {
          float w = w1g[c * K1_ + 2 * m];
          a0 += w * wEa[m]; a1 += w * wEa[m + 1];
        }
#pragma unroll
        for (int m = 0; m < 7; ++m) {
          float w = w1g[c * K1_ + 2 * m + 1];
          a0 += w * wOa[m]; a1 += w * wOa[m + 1];
        }
        x1E[cl * X1ST_ + tid] = fmaxf(sc * a0 + sh, 0.f);
        x1O[cl * X1ST_ + tid] = fmaxf(sc * a1 + sh, 0.f);
      }
      // iter 1: j = tid + 192
      if (act1) {
        float a0 = bc, a1 = bc;
#pragma unroll
        for (int m = 0; m < 8; ++m) {
          float w = w1g[c * K1_ + 2 * m];
          a0 += w * wEb[m]; a1 += w * wEb[m + 1];
        }
#pragma unroll
        for (int m = 0; m < 7; ++m) {
          float w = w1g[c * K1_ + 2 * m + 1];
          a0 += w * wOb[m]; a1 += w * wOb[m + 1];
        }
        x1E[cl * X1ST_ + j1] = fmaxf(sc * a0 + sh, 0.f);
        if (two1) x1O[cl * X1ST_ + j1] = fmaxf(sc * a1 + sh, 0.f);
      }
    }
    __syncthreads();

    // Phase B partial: accumulate these 5 input channels for outputs 2t,2t+1
    if (tid < 175) {
#pragma unroll 1
      for (int cl = 0; cl < 5; ++cl) {
        const int ci = g * 5 + cl;
        float xE[9], xO[8];
        {
          const float* pE = &x1E[cl * X1ST_ + 2 * tid];
          float2 e0 = *(const float2*)(pE + 0);
          float2 e1 = *(const float2*)(pE + 2);
          float2 e2 = *(const float2*)(pE + 4);
          float2 e3 = *(const float2*)(pE + 6);
          xE[0] = e0.x; xE[1] = e0.y; xE[2] = e1.x; xE[3] = e1.y;
          xE[4] = e2.x; xE[5] = e2.y; xE[6] = e3.x; xE[7] = e3.y;
          xE[8] = pE[8];
          const float* pO = &x1O[cl * X1ST_ + 2 * tid];
          float2 o0 = *(const float2*)(pO + 0);
          float2 o1 = *(const float2*)(pO + 2);
          float2 o2 = *(const float2*)(pO + 4);
          float2 o3 = *(const float2*)(pO + 6);
          xO[0] = o0.x; xO[1] = o0.y; xO[2] = o1.x; xO[3] = o1.y;
          xO[4] = o2.x; xO[5] = o2.y; xO[6] = o3.x; xO[7] = o3.y;
        }
#pragma unroll
        for (int co = 0; co < C2_; ++co) {
#pragma unroll
          for (int m = 0; m < 8; ++m) {
            float w = w2g[(co * C1_ + ci) * K1_ + 2 * m];
            A0[co] += w * xE[m]; A1[co] += w * xE[m + 1];
          }
#pragma unroll
          for (int m = 0; m < 7; ++m) {
            float w = w2g[(co * C1_ + ci) * K1_ + 2 * m + 1];
            A0[co] += w * xO[m]; A1[co] += w * xO[m + 1];
          }
        }
      }
    }
  }

  float t1[C2_], t2[C2_];
#pragma unroll
  for (int co = 0; co < C2_; ++co) { t1[co] = 0.f; t2[co] = 0.f; }
  if (tid < 175) {
#pragma unroll
    for (int co = 0; co < C2_; ++co) {
      float o0 = A0[co] + b2g[co];
      float o1 = A1[co] + b2g[co];
      *(float2*)&x2g[b * (C2_ * L2_) + co * L2_ + 2 * tid] = make_float2(o0, o1);
      t1[co] = o0 + o1; t2[co] = o0 * o0 + o1 * o1;
    }
  }
#pragma unroll
  for (int co = 0; co < C2_; ++co) {
#pragma unroll
    for (int off = 32; off > 0; off >>= 1) {
      t1[co] += __shfl_down(t1[co], off, 64);
      t2[co] += __shfl_down(t2[co], off, 64);
    }
  }
  if ((tid & 63) == 0) {
#pragma unroll
    for (int co = 0; co < C2_; ++co) {
      red[wid][co * 2 + 0] = t1[co];
      red[wid][co * 2 + 1] = t2[co];
    }
  }
  __syncthreads();
  if (tid < C2_ * 2) {
    float S = red[0][tid] + red[1][tid] + red[2][tid];
    part2[b * (C2_ * 2) + tid] = S;   // (b*C2 + c)*2 + s
  }
}

// ---------------- Kernel 6: fused BN2+relu+maxpool5, lin_gene, concat, mlin (2-way split) + tanh, mconv1, stats ----------------
__global__ __launch_bounds__(256) void k_gene(
    const float* __restrict__ x2g, const float* __restrict__ ac2,
    const int* __restrict__ did, const float* __restrict__ compound,
    const float* __restrict__ lgwg, const float* __restrict__ lgbg,
    const float* __restrict__ mwg, const float* __restrict__ mbg,
    const float* __restrict__ mw1g, const float* __restrict__ mb1g,
    float* __restrict__ mraw1, float* __restrict__ partm1)
{
  const int b = blockIdx.x, tid = threadIdx.x;
  __shared__ float pooled[C2_ * LP_];
  __shared__ float lgw[LP_ * LO_];
  __shared__ float cat[CAT_];
  __shared__ float mv[M_];
  __shared__ float mvp[2][M_];
  __shared__ float red1[C2_ * LM1_], red2[C2_ * LM1_];
  __shared__ float a2s[C2_], c2s[C2_];
  if (tid < C2_) { a2s[tid] = ac2[tid]; c2s[tid] = ac2[C2_ + tid]; }
  for (int i = tid; i < LP_ * LO_; i += 256) lgw[i] = lgwg[i];
  __syncthreads();
  for (int i = tid; i < C2_ * LP_; i += 256) {
    int c = i / LP_, p = i - c * LP_;
    const float* xr = x2g + (size_t)b * (C2_ * L2_) + c * L2_ + 5 * p;
    float aa = a2s[c], cc = c2s[c];
    float m = aa * xr[0] + cc;
    m = fmaxf(m, aa * xr[1] + cc);
    m = fmaxf(m, aa * xr[2] + cc);
    m = fmaxf(m, aa * xr[3] + cc);
    m = fmaxf(m, aa * xr[4] + cc);
    pooled[i] = fmaxf(m, 0.f);
  }
  __syncthreads();
  if (tid < 160) {
    int c = tid >> 5, o = tid & 31;
    float a = lgbg[o];
    for (int l = 0; l < LP_; ++l) a += pooled[c * LP_ + l] * lgw[l * LO_ + o];
    cat[tid] = fmaxf(a, 0.f);
  } else if (tid < CAT_) {
    cat[tid] = compound[did[b] * D_ + (tid - 160)];
  }
  __syncthreads();
  if (tid < 200) {
    int half = tid / 100, o = tid - half * 100;
    float a = 0.f;
    int i0 = half * 105;
    for (int i = i0; i < i0 + 105; ++i) a += cat[i] * mwg[i * M_ + o];
    mvp[half][o] = a;
  }
  __syncthreads();
  if (tid < M_) mv[tid] = tanhf(mvp[0][tid] + mvp[1][tid] + mbg[tid]);
  __syncthreads();
  if (tid < C2_ * LM1_) {
    int c = tid / LM1_, t = tid - c * LM1_;
    float a = mb1g[c];
#pragma unroll
    for (int k = 0; k < 10; ++k) a += mw1g[c * 10 + k] * mv[2 * t + k];
    mraw1[b * (C2_ * LM1_) + c * LM1_ + t] = a;
    red1[tid] = a;
    red2[tid] = a * a;
  }
  __syncthreads();
  if (tid < C2_) {
    float S1 = 0.f, S2 = 0.f;
    for (int j = 0; j < LM1_; ++j) { S1 += red1[tid * LM1_ + j]; S2 += red2[tid * LM1_ + j]; }
    partm1[(b * C2_ + tid) * 2 + 0] = S1;
    partm1[(b * C2_ + tid) * 2 + 1] = S2;
  }
}

// ---------------- Kernel 8: mbn1+maxpool3, mconv2, stats ----------------
__global__ __launch_bounds__(256) void k_mhead2(
    const float* __restrict__ mraw1, const float* __restrict__ acm1,
    const float* __restrict__ mw2g, const float* __restrict__ mb2g,
    float* __restrict__ mraw2, float* __restrict__ partm2)
{
  const int tid = threadIdx.x;
  const int b = blockIdx.x * 256 + tid;
  __shared__ float w2[C2_ * C2_ * 10];
  __shared__ float a1[C2_], c1[C2_], b2s[C2_];
  __shared__ float rw1[C2_][4], rw2[C2_][4];
  if (tid < C2_ * C2_ * 10) w2[tid] = mw2g[tid];
  if (tid < C2_) { a1[tid] = acm1[tid]; c1[tid] = acm1[C2_ + tid]; b2s[tid] = mb2g[tid]; }
  __syncthreads();
  float p[C2_ * PM1_];
  const float* row = mraw1 + (size_t)b * (C2_ * LM1_);
#pragma unroll
  for (int c = 0; c < C2_; ++c) {
    float ac = a1[c], cc = c1[c];
#pragma unroll
    for (int q = 0; q < PM1_; ++q) {
      float m = ac * row[c * LM1_ + 3 * q] + cc;
      m = fmaxf(m, ac * row[c * LM1_ + 3 * q + 1] + cc);
      m = fmaxf(m, ac * row[c * LM1_ + 3 * q + 2] + cc);
      p[c * PM1_ + q] = m;
    }
  }
#pragma unroll
  for (int co = 0; co < C2_; ++co) {
    float t1 = 0.f, t2 = 0.f;
#pragma unroll
    for (int l = 0; l < LM2_; ++l) {
      float a = b2s[co];
#pragma unroll
      for (int ci = 0; ci < C2_; ++ci)
#pragma unroll
        for (int k = 0; k < 10; ++k)
          a += w2[(co * C2_ + ci) * 10 + k] * p[ci * PM1_ + 2 * l + k];
      mraw2[b * (C2_ * LM2_) + co * LM2_ + l] = a;
      t1 += a; t2 += a * a;
    }
#pragma unroll
    for (int off = 32; off > 0; off >>= 1) {
      t1 += __shfl_down(t1, off, 64);
      t2 += __shfl_down(t2, off, 64);
    }
    if ((tid & 63) == 0) { rw1[co][tid >> 6] = t1; rw2[co][tid >> 6] = t2; }
  }
  __syncthreads();
  if (tid < C2_ * 2) {
    int co = tid >> 1, s = tid & 1;
    float S = 0.f;
#pragma unroll
    for (int w = 0; w < 4; ++w) S += (s ? rw2[co][w] : rw1[co][w]);
    partm2[blockIdx.x * (C2_ * 2) + tid] = S;
  }
}

// ---------------- Kernel 10: mbn2 + maxpool3 + output layer ----------------
__global__ __launch_bounds__(256) void k_final(
    const float* __restrict__ mraw2, const float* __restrict__ acm2,
    const float* __restrict__ owg, const float* __restrict__ obg,
    float* __restrict__ out)
{
  const int b = blockIdx.x * 256 + threadIdx.x;
  float y = obg[0];
#pragma unroll
  for (int c = 0; c < C2_; ++c) {
    float a = acm2[c], cc = acm2[C2_ + c];
    float m = a * mraw2[b * 15 + c * 3 + 0] + cc;
    m = fmaxf(m, a * mraw2[b * 15 + c * 3 + 1] + cc);
    m = fmaxf(m, a * mraw2[b * 15 + c * 3 + 2] + cc);
    y += owg[c] * m;
  }
  out[b] = y;
}

extern "C" void kernel_launch(void* const* d_in, const int* in_sizes, int n_in,
                              void* d_out, int out_size, void* d_ws, size_t ws_size,
                              hipStream_t stream) {
  (void)in_sizes; (void)n_in; (void)out_size; (void)ws_size;
  const float* rma   = (const float*)d_in[0];
  const float* varr  = (const float*)d_in[1];
  const int*   did   = (const int*)d_in[2];
  const float* fw    = (const float*)d_in[3];
  const float* sim   = (const float*)d_in[4];
  const float* embed = (const float*)d_in[5];
  const float* gW    = (const float*)d_in[6];
  const float* gb    = (const float*)d_in[7];
  const int*   fp    = (const int*)d_in[8];
  const float* adj   = (const float*)d_in[9];
  const float* w1g   = (const float*)d_in[10];
  const float* b1g   = (const float*)d_in[11];
  const float* bn1g  = (const float*)d_in[12];
  const float* bn1b  = (const float*)d_in[13];
  const float* w2g   = (const float*)d_in[14];
  const float* b2g   = (const float*)d_in[15];
  const float* bn2g  = (const float*)d_in[16];
  const float* bn2b  = (const float*)d_in[17];
  const float* lgwg  = (const float*)d_in[18];
  const float* lgbg  = (const float*)d_in[19];
  const float* mwg   = (const float*)d_in[20];
  const float* mbg   = (const float*)d_in[21];
  const float* mw1g  = (const float*)d_in[22];
  const float* mb1g  = (const float*)d_in[23];
  const float* mbn1g = (const float*)d_in[24];
  const float* mbn1b = (const float*)d_in[25];
  const float* mw2g  = (const float*)d_in[26];
  const float* mb2g  = (const float*)d_in[27];
  const float* mbn2g = (const float*)d_in[28];
  const float* mbn2b = (const float*)d_in[29];
  const float* owg   = (const float*)d_in[30];
  const float* obg   = (const float*)d_in[31];
  float* out = (float*)d_out;

  float* ws = (float*)d_ws;
  size_t o = 0;
  float* P        = ws + o; o += (size_t)DR_ * NG_;
  float* compound = ws + o; o += (size_t)DR_ * D_;
  float* comg     = ws + o; o += (size_t)B_ * NG_;
  float* part1    = ws + o; o += (size_t)B_ * C1_ * 2;
  float* ac1      = ws + o; o += 2 * C1_;
  float* x2g      = ws + o; o += (size_t)B_ * C2_ * L2_;
  float* part2    = ws + o; o += (size_t)B_ * C2_ * 2;
  float* ac2      = ws + o; o += 2 * C2_;
  float* mraw1    = ws + o; o += (size_t)B_ * C2_ * LM1_;
  float* partm1   = ws + o; o += (size_t)B_ * C2_ * 2;
  float* acm1     = ws + o; o += 2 * C2_;
  float* mraw2    = ws + o; o += (size_t)B_ * C2_ * LM2_;
  float* partm2   = ws + o; o += 16 * C2_ * 2;
  float* acm2     = ws + o; o += 2 * C2_;

  hipLaunchKernelGGL(k_fusegnn, dim3(NFUSE_ + DR_), dim3(256), 0, stream,
                     fw, sim, P, embed, gW, gb, fp, adj, compound);
  hipLaunchKernelGGL(k_conv1, dim3(B_), dim3(384), 0, stream,
                     rma, varr, did, P, w1g, b1g, comg, part1);
  hipLaunchKernelGGL(k_bnfin, dim3(C1_), dim3(256), 0, stream,
                     part1, B_, C1_, (float)B_ * (float)L1_, bn1g, bn1b, ac1);
  hipLaunchKernelGGL(k_conv2, dim3(B_), dim3(192), 0, stream,
                     comg, w1g, b1g, ac1, w2g, b2g, x2g, part2);
  hipLaunchKernelGGL(k_bnfin, dim3(C2_), dim3(256), 0, stream,
                     part2, B_, C2_, (float)B_ * (float)L2_, bn2g, bn2b, ac2);
  hipLaunchKernelGGL(k_gene, dim3(B_), dim3(256), 0, stream,
                     x2g, ac2, did, compound, lgwg, lgbg, mwg, mbg, mw1g, mb1g,
                     mraw1, partm1);
  hipLaunchKernelGGL(k_bnfin, dim3(C2_), dim3(256), 0, stream,
                     partm1, B_, C2_, (float)B_ * (float)LM1_, mbn1g, mbn1b, acm1);
  hipLaunchKernelGGL(k_mhead2, dim3(16), dim3(256), 0, stream,
                     mraw1, acm1, mw2g, mb2g, mraw2, partm2);
  hipLaunchKernelGGL(k_bnfin, dim3(C2_), dim3(256), 0, stream,
                     partm2, 16, C2_, (float)B_ * (float)LM2_, mbn2g, mbn2b, acm2);
  hipLaunchKernelGGL(k_final, dim3(16), dim3(256), 0, stream,
                     mraw2, acm2, owg, obg, out);
}

// Round 15
// 247.610 us; speedup vs baseline: 2.1574x; 2.1574x over previous
//
#include <hip/hip_runtime.h>

#define EPS 1e-5f

#define B_   4096
#define NG_  1440
#define DR_  222
#define D_   50
#define NA_  64
#define LG_  3
#define L1_  713
#define C1_  10
#define K1_  15
#define L2_  350
#define C2_  5
#define LP_  70
#define LO_  32
#define CAT_ 210
#define M_   100
#define LM1_ 46
#define PM1_ 15
#define LM2_ 3

#define X1ST_ 360     // x1E/x1O row stride (>= 357)
#define NFUSE_ 666    // fuse blocks (111 drug-pairs x 6 gene-chunks)

// ---------------- Kernel 1: fused {P = sim @ clip(fw)} + {GNN} ----------------
// blocks [0,666): fuse; blocks [666, 888): gnn (independent work, co-resident)
// NOTE: __launch_bounds__(256) is REQUIRED — without it hipcc assumes 1024-thread
// blocks and caps VGPR at 64, spilling the GNN branch's Ar[64]+xs[52] to scratch
// (R14: 800 MB of HBM scratch traffic, 6x regression).
__global__ __launch_bounds__(256) void k_fusegnn(
    const float* __restrict__ fw, const float* __restrict__ sim,
    float* __restrict__ P,
    const float* __restrict__ embed, const float* __restrict__ gW,
    const float* __restrict__ gb, const int* __restrict__ fp,
    const float* __restrict__ adj, float* __restrict__ compound)
{
  const int bx = blockIdx.x;
  const int tid = threadIdx.x;
  __shared__ float s0[DR_], s1[DR_];
  __shared__ __align__(16) float WT[D_ * 52];
  __shared__ __align__(16) float hsl[NA_ * 52];
  __shared__ float xsl[NA_ * 53];
  __shared__ float bl[D_];
  __shared__ int fps[NA_];

  if (bx < NFUSE_) {
    const int d0 = (bx / 6) * 2;
    const int g = (bx % 6) * 256 + tid;
    for (int r = tid; r < DR_; r += 256) {
      s0[r] = sim[d0 * DR_ + r];
      s1[r] = sim[(d0 + 1) * DR_ + r];
    }
    __syncthreads();
    if (g >= NG_) return;
    float a0 = 0.f, a1 = 0.f;
#pragma unroll 6
    for (int r = 0; r < DR_; ++r) {
      float w = fw[r * NG_ + g];
      w = fminf(fmaxf(w, 0.f), 1.f);
      a0 += s0[r] * w;
      a1 += s1[r] * w;
    }
    P[d0 * NG_ + g] = a0;
    P[(d0 + 1) * NG_ + g] = a1;
    return;
  }

  // ---- GNN branch ----
  const int d = bx - NFUSE_;
  const int wid = tid >> 6, lane = tid & 63;

  if (tid < NA_) fps[tid] = fp[d * NA_ + tid];
  if (wid == 0) { hsl[lane * 52 + 50] = 0.f; hsl[lane * 52 + 51] = 0.f; }
  __syncthreads();

  float xs[52];
  const float* erow = embed + (size_t)fps[lane] * D_;
#pragma unroll
  for (int j = 0; j < D_; ++j) xs[j] = erow[j];
  xs[50] = 0.f; xs[51] = 0.f;
  float Ar[NA_];
  const float* arow = adj + (size_t)d * NA_ * NA_ + lane * NA_;
#pragma unroll
  for (int j = 0; j < NA_; ++j) Ar[j] = arow[j];

  const int e0 = (wid < 2) ? wid * 13 : 26 + (wid - 2) * 12;
  const int ecnt = (wid < 2) ? 13 : 12;

  for (int layer = 0; layer < LG_; ++layer) {
    const float* Wg = gW + layer * D_ * D_;
    for (int i = tid; i < D_ * 52; i += 256) {
      int e = i / 52, dd = i - e * 52;
      WT[i] = (dd < D_) ? Wg[dd * D_ + e] : 0.f;
    }
    if (tid < D_) bl[tid] = gb[layer * D_ + tid];
    __syncthreads();

    for (int ei = 0; ei < ecnt; ++ei) {
      int e = e0 + ei;
      float c0 = bl[e], c1 = 0.f, c2 = 0.f, c3 = 0.f;
#pragma unroll
      for (int c = 0; c < 13; ++c) {
        float4 wv = *(const float4*)&WT[e * 52 + 4 * c];
        c0 += xs[4 * c + 0] * wv.x;
        c1 += xs[4 * c + 1] * wv.y;
        c2 += xs[4 * c + 2] * wv.z;
        c3 += xs[4 * c + 3] * wv.w;
      }
      hsl[lane * 52 + e] = fmaxf((c0 + c1) + (c2 + c3), 0.f);
    }
    __syncthreads();

    for (int c = wid; c < 13; c += 4) {
      float a0 = 0.f, a1 = 0.f, a2 = 0.f, a3 = 0.f;
#pragma unroll
      for (int m = 0; m < NA_; ++m) {
        float4 hv = *(const float4*)&hsl[m * 52 + 4 * c];
        float am = Ar[m];
        a0 += am * hv.x; a1 += am * hv.y; a2 += am * hv.z; a3 += am * hv.w;
      }
      int dd = 4 * c;
      xsl[lane * 53 + dd + 0] = xs[dd + 0] + a0;
      xsl[lane * 53 + dd + 1] = xs[dd + 1] + a1;
      if (dd + 2 < D_) {
        xsl[lane * 53 + dd + 2] = xs[dd + 2] + a2;
        xsl[lane * 53 + dd + 3] = xs[dd + 3] + a3;
      }
    }
    __syncthreads();
#pragma unroll
    for (int j = 0; j < D_; ++j) xs[j] = xsl[lane * 53 + j];
    __syncthreads();
  }

  if (wid == 0 && lane < D_) {
    float s = 0.f;
    for (int n = 0; n < NA_; ++n) s += xsl[n * 53 + lane];
    compound[d * D_ + lane] = s * (1.f / NA_);
  }
}

// ---------------- Kernel 2: com (register-direct) + comg store + conv1 stats ----------------
__global__ __launch_bounds__(384, 4) void k_conv1(
    const float* __restrict__ rma, const float* __restrict__ varr,
    const int* __restrict__ did, const float* __restrict__ P,
    const float* __restrict__ w1g, const float* __restrict__ b1g,
    float* __restrict__ comg, float* __restrict__ part1)
{
  const int b = blockIdx.x, tid = threadIdx.x;
  const int wid = tid >> 6;
  __shared__ float red[6][C1_ * 2];
  const int dd = did[b];
  const float* rb = rma  + (size_t)b * NG_ + 4 * tid;
  const float* vb = varr + (size_t)b * NG_ + 4 * tid;
  const float* pp = P    + (size_t)dd * NG_ + 4 * tid;

  float s1[C1_], s2[C1_];
#pragma unroll
  for (int c = 0; c < C1_; ++c) { s1[c] = 0.f; s2[c] = 0.f; }

  if (tid < 357) {
    float4 r0 = *(const float4*)(rb + 0),  r1 = *(const float4*)(rb + 4);
    float4 r2 = *(const float4*)(rb + 8),  r3 = *(const float4*)(rb + 12);
    float4 v0 = *(const float4*)(vb + 0),  v1 = *(const float4*)(vb + 4);
    float4 v2 = *(const float4*)(vb + 8),  v3 = *(const float4*)(vb + 12);
    float4 p0 = *(const float4*)(pp + 0),  p1 = *(const float4*)(pp + 4);
    float4 p2 = *(const float4*)(pp + 8),  p3 = *(const float4*)(pp + 12);
    const bool two = (tid < 356);
    float wE[9], wO[8];
    wE[0] = r0.x + p0.x * v0.x;  wO[0] = r0.y + p0.y * v0.y;
    wE[1] = r0.z + p0.z * v0.z;  wO[1] = r0.w + p0.w * v0.w;
    wE[2] = r1.x + p1.x * v1.x;  wO[2] = r1.y + p1.y * v1.y;
    wE[3] = r1.z + p1.z * v1.z;  wO[3] = r1.w + p1.w * v1.w;
    wE[4] = r2.x + p2.x * v2.x;  wO[4] = r2.y + p2.y * v2.y;
    wE[5] = r2.z + p2.z * v2.z;  wO[5] = r2.w + p2.w * v2.w;
    wE[6] = r3.x + p3.x * v3.x;  wO[6] = r3.y + p3.y * v3.y;
    wE[7] = r3.z + p3.z * v3.z;  wO[7] = r3.w + p3.w * v3.w;
    wE[8] = two ? (rb[16] + pp[16] * vb[16]) : 0.f;
    *(float4*)&comg[(size_t)b * NG_ + 4 * tid] =
        make_float4(wE[0], wO[0], wE[1], wO[1]);
#pragma unroll
    for (int c = 0; c < C1_; ++c) {
      float a0 = b1g[c], a1 = a0;
#pragma unroll
      for (int m = 0; m < 8; ++m) {
        float w = w1g[c * K1_ + 2 * m];
        a0 += w * wE[m]; a1 += w * wE[m + 1];
      }
#pragma unroll
      for (int m = 0; m < 7; ++m) {
        float w = w1g[c * K1_ + 2 * m + 1];
        a0 += w * wO[m]; a1 += w * wO[m + 1];
      }
      s1[c] = a0; s2[c] = a0 * a0;
      if (two) { s1[c] += a1; s2[c] += a1 * a1; }
    }
  } else if (tid < 360) {
    float4 r0 = *(const float4*)(rb);
    float4 v0 = *(const float4*)(vb);
    float4 p0 = *(const float4*)(pp);
    *(float4*)&comg[(size_t)b * NG_ + 4 * tid] =
        make_float4(r0.x + p0.x * v0.x, r0.y + p0.y * v0.y,
                    r0.z + p0.z * v0.z, r0.w + p0.w * v0.w);
  }

#pragma unroll
  for (int c = 0; c < C1_; ++c) {
#pragma unroll
    for (int off = 32; off > 0; off >>= 1) {
      s1[c] += __shfl_down(s1[c], off, 64);
      s2[c] += __shfl_down(s2[c], off, 64);
    }
  }
  if ((tid & 63) == 0) {
#pragma unroll
    for (int c = 0; c < C1_; ++c) {
      red[wid][c * 2 + 0] = s1[c];
      red[wid][c * 2 + 1] = s2[c];
    }
  }
  __syncthreads();
  if (tid < C1_ * 2) {
    float S = 0.f;
#pragma unroll
    for (int w = 0; w < 6; ++w) S += red[w][tid];
    part1[b * (C1_ * 2) + tid] = S;   // (b*C1 + c)*2 + s
  }
}

// ---------------- BN finalize ----------------
__global__ __launch_bounds__(256) void k_bnfin(
    const float* __restrict__ part, int nblk, int C, float N,
    const float* __restrict__ g, const float* __restrict__ bta,
    float* __restrict__ ac)
{
  const int c = blockIdx.x, tid = threadIdx.x;
  float s1 = 0.f, s2 = 0.f;
  for (int j = tid; j < nblk; j += 256) {
    s1 += part[(j * C + c) * 2 + 0];
    s2 += part[(j * C + c) * 2 + 1];
  }
#pragma unroll
  for (int off = 32; off > 0; off >>= 1) {
    s1 += __shfl_down(s1, off, 64);
    s2 += __shfl_down(s2, off, 64);
  }
  __shared__ float r1[4], r2[4];
  int w = tid >> 6;
  if ((tid & 63) == 0) { r1[w] = s1; r2[w] = s2; }
  __syncthreads();
  if (tid == 0) {
    float S1 = r1[0] + r1[1] + r1[2] + r1[3];
    float S2 = r2[0] + r2[1] + r2[2] + r2[3];
    float mean = S1 / N;
    float v = S2 / N - mean * mean;
    float a = g[c] * rsqrtf(v + EPS);
    ac[c] = a;
    ac[C + c] = bta[c] - mean * a;
  }
}

// ---------------- Kernel 4: channel-split half-LDS double-pass; reg-cached windows; b64 phase-B reads ----------------
__global__ __launch_bounds__(192, 6) void k_conv2(
    const float* __restrict__ comg, const float* __restrict__ w1g,
    const float* __restrict__ b1g, const float* __restrict__ ac1,
    const float* __restrict__ w2g, const float* __restrict__ b2g,
    float* __restrict__ x2g, float* __restrict__ part2)
{
  const int b = blockIdx.x, tid = threadIdx.x;
  const int wid = tid >> 6;                 // 0..2
  __shared__ __align__(8) float x1E[5 * X1ST_], x1O[5 * X1ST_];
  __shared__ float red[3][C2_ * 2];

  // Load both j-iterations' windows ONCE into registers (reused by both g passes)
  const int j1 = tid + 192;
  const bool act1 = (j1 < 357);         // tid < 165
  const bool two1 = (j1 < 356);         // tid < 164
  float wEa[9], wOa[8], wEb[9], wOb[8];
  {
    const float* base = comg + (size_t)b * NG_ + 4 * tid;
    float4 v0 = *(const float4*)(base + 0);
    float4 v1 = *(const float4*)(base + 4);
    float4 v2 = *(const float4*)(base + 8);
    float4 v3 = *(const float4*)(base + 12);
    wEa[0] = v0.x; wEa[1] = v0.z; wEa[2] = v1.x; wEa[3] = v1.z;
    wEa[4] = v2.x; wEa[5] = v2.z; wEa[6] = v3.x; wEa[7] = v3.z;
    wEa[8] = base[16];
    wOa[0] = v0.y; wOa[1] = v0.w; wOa[2] = v1.y; wOa[3] = v1.w;
    wOa[4] = v2.y; wOa[5] = v2.w; wOa[6] = v3.y; wOa[7] = v3.w;
  }
  if (act1) {
    const float* base = comg + (size_t)b * NG_ + 4 * j1;
    float4 v0 = *(const float4*)(base + 0);
    float4 v1 = *(const float4*)(base + 4);
    float4 v2 = *(const float4*)(base + 8);
    float4 v3 = *(const float4*)(base + 12);
    wEb[0] = v0.x; wEb[1] = v0.z; wEb[2] = v1.x; wEb[3] = v1.z;
    wEb[4] = v2.x; wEb[5] = v2.z; wEb[6] = v3.x; wEb[7] = v3.z;
    wEb[8] = two1 ? base[16] : 0.f;
    wOb[0] = v0.y; wOb[1] = v0.w; wOb[2] = v1.y; wOb[3] = v1.w;
    wOb[4] = v2.y; wOb[5] = v2.w; wOb[6] = v3.y; wOb[7] = v3.w;
  }

  float A0[C2_], A1[C2_];
#pragma unroll
  for (int co = 0; co < C2_; ++co) { A0[co] = 0.f; A1[co] = 0.f; }

#pragma unroll 1
  for (int g = 0; g < 2; ++g) {
    if (g) __syncthreads();   // previous phase B done before overwriting x1
    // Phase A: conv1+BN1+relu for channels g*5..g*5+4, from cached windows
#pragma unroll 1
    for (int cl = 0; cl < 5; ++cl) {
      const int c = g * 5 + cl;
      const float bc = b1g[c];
      const float sc = ac1[c], sh = ac1[C1_ + c];
      {
        float a0 = bc, a1 = bc;
#pragma unroll
        for (int m = 0; m < 8; ++m) {
          float w = w1g[c * K1_ + 2 * m];
          a0 += w * wEa[m]; a1 += w * wEa[m + 1];
        }
#pragma unroll
        for (int m = 0; m < 7; ++m) {
          float w = w1g[c * K1_ + 2 * m + 1];
          a0 += w * wOa[m]; a1 += w * wOa[m + 1];
        }
        x1E[cl * X1ST_ + tid] = fmaxf(sc * a0 + sh, 0.f);
        x1O[cl * X1ST_ + tid] = fmaxf(sc * a1 + sh, 0.f);
      }
      if (act1) {
        float a0 = bc, a1 = bc;
#pragma unroll
        for (int m = 0; m < 8; ++m) {
          float w = w1g[c * K1_ + 2 * m];
          a0 += w * wEb[m]; a1 += w * wEb[m + 1];
        }
#pragma unroll
        for (int m = 0; m < 7; ++m) {
          float w = w1g[c * K1_ + 2 * m + 1];
          a0 += w * wOb[m]; a1 += w * wOb[m + 1];
        }
        x1E[cl * X1ST_ + j1] = fmaxf(sc * a0 + sh, 0.f);
        if (two1) x1O[cl * X1ST_ + j1] = fmaxf(sc * a1 + sh, 0.f);
      }
    }
    __syncthreads();

    // Phase B partial: accumulate these 5 input channels for outputs 2t,2t+1
    if (tid < 175) {
#pragma unroll 1
      for (int cl = 0; cl < 5; ++cl) {
        const int ci = g * 5 + cl;
        float xE[9], xO[8];
        {
          const float* pE = &x1E[cl * X1ST_ + 2 * tid];
          float2 e0 = *(const float2*)(pE + 0);
          float2 e1 = *(const float2*)(pE + 2);
          float2 e2 = *(const float2*)(pE + 4);
          float2 e3 = *(const float2*)(pE + 6);
          xE[0] = e0.x; xE[1] = e0.y; xE[2] = e1.x; xE[3] = e1.y;
          xE[4] = e2.x; xE[5] = e2.y; xE[6] = e3.x; xE[7] = e3.y;
          xE[8] = pE[8];
          const float* pO = &x1O[cl * X1ST_ + 2 * tid];
          float2 o0 = *(const float2*)(pO + 0);
          float2 o1 = *(const float2*)(pO + 2);
          float2 o2 = *(const float2*)(pO + 4);
          float2 o3 = *(const float2*)(pO + 6);
          xO[0] = o0.x; xO[1] = o0.y; xO[2] = o1.x; xO[3] = o1.y;
          xO[4] = o2.x; xO[5] = o2.y; xO[6] = o3.x; xO[7] = o3.y;
        }
#pragma unroll
        for (int co = 0; co < C2_; ++co) {
#pragma unroll
          for (int m = 0; m < 8; ++m) {
            float w = w2g[(co * C1_ + ci) * K1_ + 2 * m];
            A0[co] += w * xE[m]; A1[co] += w * xE[m + 1];
          }
#pragma unroll
          for (int m = 0; m < 7; ++m) {
            float w = w2g[(co * C1_ + ci) * K1_ + 2 * m + 1];
            A0[co] += w * xO[m]; A1[co] += w * xO[m + 1];
          }
        }
      }
    }
  }

  float t1[C2_], t2[C2_];
#pragma unroll
  for (int co = 0; co < C2_; ++co) { t1[co] = 0.f; t2[co] = 0.f; }
  if (tid < 175) {
#pragma unroll
    for (int co = 0; co < C2_; ++co) {
      float o0 = A0[co] + b2g[co];
      float o1 = A1[co] + b2g[co];
      *(float2*)&x2g[b * (C2_ * L2_) + co * L2_ + 2 * tid] = make_float2(o0, o1);
      t1[co] = o0 + o1; t2[co] = o0 * o0 + o1 * o1;
    }
  }
#pragma unroll
  for (int co = 0; co < C2_; ++co) {
#pragma unroll
    for (int off = 32; off > 0; off >>= 1) {
      t1[co] += __shfl_down(t1[co], off, 64);
      t2[co] += __shfl_down(t2[co], off, 64);
    }
  }
  if ((tid & 63) == 0) {
#pragma unroll
    for (int co = 0; co < C2_; ++co) {
      red[wid][co * 2 + 0] = t1[co];
      red[wid][co * 2 + 1] = t2[co];
    }
  }
  __syncthreads();
  if (tid < C2_ * 2) {
    float S = red[0][tid] + red[1][tid] + red[2][tid];
    part2[b * (C2_ * 2) + tid] = S;   // (b*C2 + c)*2 + s
  }
}

// ---------------- Kernel 6: fused BN2+relu+maxpool5, lin_gene, concat, mlin (2-way split) + tanh, mconv1, stats ----------------
__global__ __launch_bounds__(256) void k_gene(
    const float* __restrict__ x2g, const float* __restrict__ ac2,
    const int* __restrict__ did, const float* __restrict__ compound,
    const float* __restrict__ lgwg, const float* __restrict__ lgbg,
    const float* __restrict__ mwg, const float* __restrict__ mbg,
    const float* __restrict__ mw1g, const float* __restrict__ mb1g,
    float* __restrict__ mraw1, float* __restrict__ partm1)
{
  const int b = blockIdx.x, tid = threadIdx.x;
  __shared__ float pooled[C2_ * LP_];
  __shared__ float lgw[LP_ * LO_];
  __shared__ float cat[CAT_];
  __shared__ float mv[M_];
  __shared__ float mvp[2][M_];
  __shared__ float red1[C2_ * LM1_], red2[C2_ * LM1_];
  __shared__ float a2s[C2_], c2s[C2_];
  if (tid < C2_) { a2s[tid] = ac2[tid]; c2s[tid] = ac2[C2_ + tid]; }
  for (int i = tid; i < LP_ * LO_; i += 256) lgw[i] = lgwg[i];
  __syncthreads();
  for (int i = tid; i < C2_ * LP_; i += 256) {
    int c = i / LP_, p = i - c * LP_;
    const float* xr = x2g + (size_t)b * (C2_ * L2_) + c * L2_ + 5 * p;
    float aa = a2s[c], cc = c2s[c];
    float m = aa * xr[0] + cc;
    m = fmaxf(m, aa * xr[1] + cc);
    m = fmaxf(m, aa * xr[2] + cc);
    m = fmaxf(m, aa * xr[3] + cc);
    m = fmaxf(m, aa * xr[4] + cc);
    pooled[i] = fmaxf(m, 0.f);
  }
  __syncthreads();
  if (tid < 160) {
    int c = tid >> 5, o = tid & 31;
    float a = lgbg[o];
    for (int l = 0; l < LP_; ++l) a += pooled[c * LP_ + l] * lgw[l * LO_ + o];
    cat[tid] = fmaxf(a, 0.f);
  } else if (tid < CAT_) {
    cat[tid] = compound[did[b] * D_ + (tid - 160)];
  }
  __syncthreads();
  if (tid < 200) {
    int half = tid / 100, o = tid - half * 100;
    float a = 0.f;
    int i0 = half * 105;
    for (int i = i0; i < i0 + 105; ++i) a += cat[i] * mwg[i * M_ + o];
    mvp[half][o] = a;
  }
  __syncthreads();
  if (tid < M_) mv[tid] = tanhf(mvp[0][tid] + mvp[1][tid] + mbg[tid]);
  __syncthreads();
  if (tid < C2_ * LM1_) {
    int c = tid / LM1_, t = tid - c * LM1_;
    float a = mb1g[c];
#pragma unroll
    for (int k = 0; k < 10; ++k) a += mw1g[c * 10 + k] * mv[2 * t + k];
    mraw1[b * (C2_ * LM1_) + c * LM1_ + t] = a;
    red1[tid] = a;
    red2[tid] = a * a;
  }
  __syncthreads();
  if (tid < C2_) {
    float S1 = 0.f, S2 = 0.f;
    for (int j = 0; j < LM1_; ++j) { S1 += red1[tid * LM1_ + j]; S2 += red2[tid * LM1_ + j]; }
    partm1[(b * C2_ + tid) * 2 + 0] = S1;
    partm1[(b * C2_ + tid) * 2 + 1] = S2;
  }
}

// ---------------- Kernel 8: mbn1+maxpool3, mconv2, stats ----------------
__global__ __launch_bounds__(256) void k_mhead2(
    const float* __restrict__ mraw1, const float* __restrict__ acm1,
    const float* __restrict__ mw2g, const float* __restrict__ mb2g,
    float* __restrict__ mraw2, float* __restrict__ partm2)
{
  const int tid = threadIdx.x;
  const int b = blockIdx.x * 256 + tid;
  __shared__ float w2[C2_ * C2_ * 10];
  __shared__ float a1[C2_], c1[C2_], b2s[C2_];
  __shared__ float rw1[C2_][4], rw2[C2_][4];
  if (tid < C2_ * C2_ * 10) w2[tid] = mw2g[tid];
  if (tid < C2_) { a1[tid] = acm1[tid]; c1[tid] = acm1[C2_ + tid]; b2s[tid] = mb2g[tid]; }
  __syncthreads();
  float p[C2_ * PM1_];
  const float* row = mraw1 + (size_t)b * (C2_ * LM1_);
#pragma unroll
  for (int c = 0; c < C2_; ++c) {
    float ac = a1[c], cc = c1[c];
#pragma unroll
    for (int q = 0; q < PM1_; ++q) {
      float m = ac * row[c * LM1_ + 3 * q] + cc;
      m = fmaxf(m, ac * row[c * LM1_ + 3 * q + 1] + cc);
      m = fmaxf(m, ac * row[c * LM1_ + 3 * q + 2] + cc);
      p[c * PM1_ + q] = m;
    }
  }
#pragma unroll
  for (int co = 0; co < C2_; ++co) {
    float t1 = 0.f, t2 = 0.f;
#pragma unroll
    for (int l = 0; l < LM2_; ++l) {
      float a = b2s[co];
#pragma unroll
      for (int ci = 0; ci < C2_; ++ci)
#pragma unroll
        for (int k = 0; k < 10; ++k)
          a += w2[(co * C2_ + ci) * 10 + k] * p[ci * PM1_ + 2 * l + k];
      mraw2[b * (C2_ * LM2_) + co * LM2_ + l] = a;
      t1 += a; t2 += a * a;
    }
#pragma unroll
    for (int off = 32; off > 0; off >>= 1) {
      t1 += __shfl_down(t1, off, 64);
      t2 += __shfl_down(t2, off, 64);
    }
    if ((tid & 63) == 0) { rw1[co][tid >> 6] = t1; rw2[co][tid >> 6] = t2; }
  }
  __syncthreads();
  if (tid < C2_ * 2) {
    int co = tid >> 1, s = tid & 1;
    float S = 0.f;
#pragma unroll
    for (int w = 0; w < 4; ++w) S += (s ? rw2[co][w] : rw1[co][w]);
    partm2[blockIdx.x * (C2_ * 2) + tid] = S;
  }
}

// ---------------- Kernel 10: mbn2 + maxpool3 + output layer ----------------
__global__ __launch_bounds__(256) void k_final(
    const float* __restrict__ mraw2, const float* __restrict__ acm2,
    const float* __restrict__ owg, const float* __restrict__ obg,
    float* __restrict__ out)
{
  const int b = blockIdx.x * 256 + threadIdx.x;
  float y = obg[0];
#pragma unroll
  for (int c = 0; c < C2_; ++c) {
    float a = acm2[c], cc = acm2[C2_ + c];
    float m = a * mraw2[b * 15 + c * 3 + 0] + cc;
    m = fmaxf(m, a * mraw2[b * 15 + c * 3 + 1] + cc);
    m = fmaxf(m, a * mraw2[b * 15 + c * 3 + 2] + cc);
    y += owg[c] * m;
  }
  out[b] = y;
}

extern "C" void kernel_launch(void* const* d_in, const int* in_sizes, int n_in,
                              void* d_out, int out_size, void* d_ws, size_t ws_size,
                              hipStream_t stream) {
  (void)in_sizes; (void)n_in; (void)out_size; (void)ws_size;
  const float* rma   = (const float*)d_in[0];
  const float* varr  = (const float*)d_in[1];
  const int*   did   = (const int*)d_in[2];
  const float* fw    = (const float*)d_in[3];
  const float* sim   = (const float*)d_in[4];
  const float* embed = (const float*)d_in[5];
  const float* gW    = (const float*)d_in[6];
  const float* gb    = (const float*)d_in[7];
  const int*   fp    = (const int*)d_in[8];
  const float* adj   = (const float*)d_in[9];
  const float* w1g   = (const float*)d_in[10];
  const float* b1g   = (const float*)d_in[11];
  const float* bn1g  = (const float*)d_in[12];
  const float* bn1b  = (const float*)d_in[13];
  const float* w2g   = (const float*)d_in[14];
  const float* b2g   = (const float*)d_in[15];
  const float* bn2g  = (const float*)d_in[16];
  const float* bn2b  = (const float*)d_in[17];
  const float* lgwg  = (const float*)d_in[18];
  const float* lgbg  = (const float*)d_in[19];
  const float* mwg   = (const float*)d_in[20];
  const float* mbg   = (const float*)d_in[21];
  const float* mw1g  = (const float*)d_in[22];
  const float* mb1g  = (const float*)d_in[23];
  const float* mbn1g = (const float*)d_in[24];
  const float* mbn1b = (const float*)d_in[25];
  const float* mw2g  = (const float*)d_in[26];
  const float* mb2g  = (const float*)d_in[27];
  const float* mbn2g = (const float*)d_in[28];
  const float* mbn2b = (const float*)d_in[29];
  const float* owg   = (const float*)d_in[30];
  const float* obg   = (const float*)d_in[31];
  float* out = (float*)d_out;

  float* ws = (float*)d_ws;
  size_t o = 0;
  float* P        = ws + o; o += (size_t)DR_ * NG_;
  float* compound = ws + o; o += (size_t)DR_ * D_;
  float* comg     = ws + o; o += (size_t)B_ * NG_;
  float* part1    = ws + o; o += (size_t)B_ * C1_ * 2;
  float* ac1      = ws + o; o += 2 * C1_;
  float* x2g      = ws + o; o += (size_t)B_ * C2_ * L2_;
  float* part2    = ws + o; o += (size_t)B_ * C2_ * 2;
  float* ac2      = ws + o; o += 2 * C2_;
  float* mraw1    = ws + o; o += (size_t)B_ * C2_ * LM1_;
  float* partm1   = ws + o; o += (size_t)B_ * C2_ * 2;
  float* acm1     = ws + o; o += 2 * C2_;
  float* mraw2    = ws + o; o += (size_t)B_ * C2_ * LM2_;
  float* partm2   = ws + o; o += 16 * C2_ * 2;
  float* acm2     = ws + o; o += 2 * C2_;

  hipLaunchKernelGGL(k_fusegnn, dim3(NFUSE_ + DR_), dim3(256), 0, stream,
                     fw, sim, P, embed, gW, gb, fp, adj, compound);
  hipLaunchKernelGGL(k_conv1, dim3(B_), dim3(384), 0, stream,
                     rma, varr, did, P, w1g, b1g, comg, part1);
  hipLaunchKernelGGL(k_bnfin, dim3(C1_), dim3(256), 0, stream,
                     part1, B_, C1_, (float)B_ * (float)L1_, bn1g, bn1b, ac1);
  hipLaunchKernelGGL(k_conv2, dim3(B_), dim3(192), 0, stream,
                     comg, w1g, b1g, ac1, w2g, b2g, x2g, part2);
  hipLaunchKernelGGL(k_bnfin, dim3(C2_), dim3(256), 0, stream,
                     part2, B_, C2_, (float)B_ * (float)L2_, bn2g, bn2b, ac2);
  hipLaunchKernelGGL(k_gene, dim3(B_), dim3(256), 0, stream,
                     x2g, ac2, did, compound, lgwg, lgbg, mwg, mbg, mw1g, mb1g,
                     mraw1, partm1);
  hipLaunchKernelGGL(k_bnfin, dim3(C2_), dim3(256), 0, stream,
                     partm1, B_, C2_, (float)B_ * (float)LM1_, mbn1g, mbn1b, acm1);
  hipLaunchKernelGGL(k_mhead2, dim3(16), dim3(256), 0, stream,
                     mraw1, acm1, mw2g, mb2g, mraw2, partm2);
  hipLaunchKernelGGL(k_bnfin, dim3(C2_), dim3(256), 0, stream,
                     partm2, 16, C2_, (float)B_ * (float)LM2_, mbn2g, mbn2b, acm2);
  hipLaunchKernelGGL(k_final, dim3(16), dim3(256), 0, stream,
                     mraw2, acm2, owg, obg, out);
}

// Round 16
// 238.255 us; speedup vs baseline: 2.2422x; 1.0393x over previous
//
#include <hip/hip_runtime.h>

#define EPS 1e-5f

#define B_   4096
#define NG_  1440
#define DR_  222
#define D_   50
#define NA_  64
#define LG_  3
#define L1_  713
#define C1_  10
#define K1_  15
#define L2_  350
#define C2_  5
#define LP_  70
#define LO_  32
#define CAT_ 210
#define M_   100
#define LM1_ 46
#define PM1_ 15
#define LM2_ 3

#define X1ST_ 360     // x1E/x1O row stride (>= 357)

// ---------------- Kernel 1a: P = sim @ clip(fw,0,1) ----------------
__global__ __launch_bounds__(256) void k_fuse(
    const float* __restrict__ fw, const float* __restrict__ sim,
    float* __restrict__ P)
{
  const int d0 = blockIdx.x * 2;
  const int g = blockIdx.y * 256 + threadIdx.x;
  const int tid = threadIdx.x;
  __shared__ float s0[DR_], s1[DR_];
  for (int r = tid; r < DR_; r += 256) {
    s0[r] = sim[d0 * DR_ + r];
    s1[r] = sim[(d0 + 1) * DR_ + r];
  }
  __syncthreads();
  if (g >= NG_) return;
  float a0 = 0.f, a1 = 0.f;
#pragma unroll 6
  for (int r = 0; r < DR_; ++r) {
    float w = fw[r * NG_ + g];
    w = fminf(fmaxf(w, 0.f), 1.f);
    a0 += s0[r] * w;
    a1 += s1[r] * w;
  }
  P[d0 * NG_ + g] = a0;
  P[(d0 + 1) * NG_ + g] = a1;
}

// ---------------- Kernel 1b: GNN, lane=node, xs & A register-resident ----------------
__global__ __launch_bounds__(256) void k_gnn(
    const float* __restrict__ embed, const float* __restrict__ gW,
    const float* __restrict__ gb, const int* __restrict__ fp,
    const float* __restrict__ adj, float* __restrict__ compound)
{
  const int d = blockIdx.x;
  const int tid = threadIdx.x;
  const int wid = tid >> 6, lane = tid & 63;
  __shared__ __align__(16) float WT[D_ * 52];
  __shared__ __align__(16) float hsl[NA_ * 52];
  __shared__ float xsl[NA_ * 53];
  __shared__ float bl[D_];
  __shared__ int fps[NA_];

  if (tid < NA_) fps[tid] = fp[d * NA_ + tid];
  if (wid == 0) { hsl[lane * 52 + 50] = 0.f; hsl[lane * 52 + 51] = 0.f; }
  __syncthreads();

  float xs[52];
  const float* erow = embed + (size_t)fps[lane] * D_;
#pragma unroll
  for (int j = 0; j < D_; ++j) xs[j] = erow[j];
  xs[50] = 0.f; xs[51] = 0.f;
  float Ar[NA_];
  const float* arow = adj + (size_t)d * NA_ * NA_ + lane * NA_;
#pragma unroll
  for (int j = 0; j < NA_; ++j) Ar[j] = arow[j];

  const int e0 = (wid < 2) ? wid * 13 : 26 + (wid - 2) * 12;
  const int ecnt = (wid < 2) ? 13 : 12;

  for (int layer = 0; layer < LG_; ++layer) {
    const float* Wg = gW + layer * D_ * D_;
    for (int i = tid; i < D_ * 52; i += 256) {
      int e = i / 52, dd = i - e * 52;
      WT[i] = (dd < D_) ? Wg[dd * D_ + e] : 0.f;
    }
    if (tid < D_) bl[tid] = gb[layer * D_ + tid];
    __syncthreads();

    for (int ei = 0; ei < ecnt; ++ei) {
      int e = e0 + ei;
      float c0 = bl[e], c1 = 0.f, c2 = 0.f, c3 = 0.f;
#pragma unroll
      for (int c = 0; c < 13; ++c) {
        float4 wv = *(const float4*)&WT[e * 52 + 4 * c];
        c0 += xs[4 * c + 0] * wv.x;
        c1 += xs[4 * c + 1] * wv.y;
        c2 += xs[4 * c + 2] * wv.z;
        c3 += xs[4 * c + 3] * wv.w;
      }
      hsl[lane * 52 + e] = fmaxf((c0 + c1) + (c2 + c3), 0.f);
    }
    __syncthreads();

    for (int c = wid; c < 13; c += 4) {
      float a0 = 0.f, a1 = 0.f, a2 = 0.f, a3 = 0.f;
#pragma unroll
      for (int m = 0; m < NA_; ++m) {
        float4 hv = *(const float4*)&hsl[m * 52 + 4 * c];
        float am = Ar[m];
        a0 += am * hv.x; a1 += am * hv.y; a2 += am * hv.z; a3 += am * hv.w;
      }
      int dd = 4 * c;
      xsl[lane * 53 + dd + 0] = xs[dd + 0] + a0;
      xsl[lane * 53 + dd + 1] = xs[dd + 1] + a1;
      if (dd + 2 < D_) {
        xsl[lane * 53 + dd + 2] = xs[dd + 2] + a2;
        xsl[lane * 53 + dd + 3] = xs[dd + 3] + a3;
      }
    }
    __syncthreads();
#pragma unroll
    for (int j = 0; j < D_; ++j) xs[j] = xsl[lane * 53 + j];
    __syncthreads();
  }

  if (wid == 0 && lane < D_) {
    float s = 0.f;
    for (int n = 0; n < NA_; ++n) s += xsl[n * 53 + lane];
    compound[d * D_ + lane] = s * (1.f / NA_);
  }
}

// ---------------- Kernel 2: com (register-direct) + comg store + conv1 stats ----------------
__global__ __launch_bounds__(384, 4) void k_conv1(
    const float* __restrict__ rma, const float* __restrict__ varr,
    const int* __restrict__ did, const float* __restrict__ P,
    const float* __restrict__ w1g, const float* __restrict__ b1g,
    float* __restrict__ comg, float* __restrict__ part1)
{
  const int b = blockIdx.x, tid = threadIdx.x;
  const int wid = tid >> 6;
  __shared__ float red[6][C1_ * 2];
  const int dd = did[b];
  const float* rb = rma  + (size_t)b * NG_ + 4 * tid;
  const float* vb = varr + (size_t)b * NG_ + 4 * tid;
  const float* pp = P    + (size_t)dd * NG_ + 4 * tid;

  float s1[C1_], s2[C1_];
#pragma unroll
  for (int c = 0; c < C1_; ++c) { s1[c] = 0.f; s2[c] = 0.f; }

  if (tid < 357) {
    float4 r0 = *(const float4*)(rb + 0),  r1 = *(const float4*)(rb + 4);
    float4 r2 = *(const float4*)(rb + 8),  r3 = *(const float4*)(rb + 12);
    float4 v0 = *(const float4*)(vb + 0),  v1 = *(const float4*)(vb + 4);
    float4 v2 = *(const float4*)(vb + 8),  v3 = *(const float4*)(vb + 12);
    float4 p0 = *(const float4*)(pp + 0),  p1 = *(const float4*)(pp + 4);
    float4 p2 = *(const float4*)(pp + 8),  p3 = *(const float4*)(pp + 12);
    const bool two = (tid < 356);
    float wE[9], wO[8];
    wE[0] = r0.x + p0.x * v0.x;  wO[0] = r0.y + p0.y * v0.y;
    wE[1] = r0.z + p0.z * v0.z;  wO[1] = r0.w + p0.w * v0.w;
    wE[2] = r1.x + p1.x * v1.x;  wO[2] = r1.y + p1.y * v1.y;
    wE[3] = r1.z + p1.z * v1.z;  wO[3] = r1.w + p1.w * v1.w;
    wE[4] = r2.x + p2.x * v2.x;  wO[4] = r2.y + p2.y * v2.y;
    wE[5] = r2.z + p2.z * v2.z;  wO[5] = r2.w + p2.w * v2.w;
    wE[6] = r3.x + p3.x * v3.x;  wO[6] = r3.y + p3.y * v3.y;
    wE[7] = r3.z + p3.z * v3.z;  wO[7] = r3.w + p3.w * v3.w;
    wE[8] = two ? (rb[16] + pp[16] * vb[16]) : 0.f;
    *(float4*)&comg[(size_t)b * NG_ + 4 * tid] =
        make_float4(wE[0], wO[0], wE[1], wO[1]);
#pragma unroll
    for (int c = 0; c < C1_; ++c) {
      float a0 = b1g[c], a1 = a0;
#pragma unroll
      for (int m = 0; m < 8; ++m) {
        float w = w1g[c * K1_ + 2 * m];
        a0 += w * wE[m]; a1 += w * wE[m + 1];
      }
#pragma unroll
      for (int m = 0; m < 7; ++m) {
        float w = w1g[c * K1_ + 2 * m + 1];
        a0 += w * wO[m]; a1 += w * wO[m + 1];
      }
      s1[c] = a0; s2[c] = a0 * a0;
      if (two) { s1[c] += a1; s2[c] += a1 * a1; }
    }
  } else if (tid < 360) {
    float4 r0 = *(const float4*)(rb);
    float4 v0 = *(const float4*)(vb);
    float4 p0 = *(const float4*)(pp);
    *(float4*)&comg[(size_t)b * NG_ + 4 * tid] =
        make_float4(r0.x + p0.x * v0.x, r0.y + p0.y * v0.y,
                    r0.z + p0.z * v0.z, r0.w + p0.w * v0.w);
  }

#pragma unroll
  for (int c = 0; c < C1_; ++c) {
#pragma unroll
    for (int off = 32; off > 0; off >>= 1) {
      s1[c] += __shfl_down(s1[c], off, 64);
      s2[c] += __shfl_down(s2[c], off, 64);
    }
  }
  if ((tid & 63) == 0) {
#pragma unroll
    for (int c = 0; c < C1_; ++c) {
      red[wid][c * 2 + 0] = s1[c];
      red[wid][c * 2 + 1] = s2[c];
    }
  }
  __syncthreads();
  if (tid < C1_ * 2) {
    float S = 0.f;
#pragma unroll
    for (int w = 0; w < 6; ++w) S += red[w][tid];
    part1[b * (C1_ * 2) + tid] = S;   // (b*C1 + c)*2 + s
  }
}

// ---------------- BN finalize ----------------
__global__ __launch_bounds__(256) void k_bnfin(
    const float* __restrict__ part, int nblk, int C, float N,
    const float* __restrict__ g, const float* __restrict__ bta,
    float* __restrict__ ac)
{
  const int c = blockIdx.x, tid = threadIdx.x;
  float s1 = 0.f, s2 = 0.f;
  for (int j = tid; j < nblk; j += 256) {
    s1 += part[(j * C + c) * 2 + 0];
    s2 += part[(j * C + c) * 2 + 1];
  }
#pragma unroll
  for (int off = 32; off > 0; off >>= 1) {
    s1 += __shfl_down(s1, off, 64);
    s2 += __shfl_down(s2, off, 64);
  }
  __shared__ float r1[4], r2[4];
  int w = tid >> 6;
  if ((tid & 63) == 0) { r1[w] = s1; r2[w] = s2; }
  __syncthreads();
  if (tid == 0) {
    float S1 = r1[0] + r1[1] + r1[2] + r1[3];
    float S2 = r2[0] + r2[1] + r2[2] + r2[3];
    float mean = S1 / N;
    float v = S2 / N - mean * mean;
    float a = g[c] * rsqrtf(v + EPS);
    ac[c] = a;
    ac[C + c] = bta[c] - mean * a;
  }
}

// ---------------- Kernel 4: channel-split half-LDS double-pass; reg-cached windows; b64 phase-B reads ----------------
__global__ __launch_bounds__(192, 6) void k_conv2(
    const float* __restrict__ comg, const float* __restrict__ w1g,
    const float* __restrict__ b1g, const float* __restrict__ ac1,
    const float* __restrict__ w2g, const float* __restrict__ b2g,
    float* __restrict__ x2g, float* __restrict__ part2)
{
  const int b = blockIdx.x, tid = threadIdx.x;
  const int wid = tid >> 6;                 // 0..2
  __shared__ __align__(8) float x1E[5 * X1ST_], x1O[5 * X1ST_];
  __shared__ float red[3][C2_ * 2];

  // Load both j-iterations' windows ONCE into registers (reused by both g passes)
  const int j1 = tid + 192;
  const bool act1 = (j1 < 357);         // tid < 165
  const bool two1 = (j1 < 356);         // tid < 164
  float wEa[9], wOa[8], wEb[9], wOb[8];
  {
    const float* base = comg + (size_t)b * NG_ + 4 * tid;
    float4 v0 = *(const float4*)(base + 0);
    float4 v1 = *(const float4*)(base + 4);
    float4 v2 = *(const float4*)(base + 8);
    float4 v3 = *(const float4*)(base + 12);
    wEa[0] = v0.x; wEa[1] = v0.z; wEa[2] = v1.x; wEa[3] = v1.z;
    wEa[4] = v2.x; wEa[5] = v2.z; wEa[6] = v3.x; wEa[7] = v3.z;
    wEa[8] = base[16];
    wOa[0] = v0.y; wOa[1] = v0.w; wOa[2] = v1.y; wOa[3] = v1.w;
    wOa[4] = v2.y; wOa[5] = v2.w; wOa[6] = v3.y; wOa[7] = v3.w;
  }
  if (act1) {
    const float* base = comg + (size_t)b * NG_ + 4 * j1;
    float4 v0 = *(const float4*)(base + 0);
    float4 v1 = *(const float4*)(base + 4);
    float4 v2 = *(const float4*)(base + 8);
    float4 v3 = *(const float4*)(base + 12);
    wEb[0] = v0.x; wEb[1] = v0.z; wEb[2] = v1.x; wEb[3] = v1.z;
    wEb[4] = v2.x; wEb[5] = v2.z; wEb[6] = v3.x; wEb[7] = v3.z;
    wEb[8] = two1 ? base[16] : 0.f;
    wOb[0] = v0.y; wOb[1] = v0.w; wOb[2] = v1.y; wOb[3] = v1.w;
    wOb[4] = v2.y; wOb[5] = v2.w; wOb[6] = v3.y; wOb[7] = v3.w;
  }

  float A0[C2_], A1[C2_];
#pragma unroll
  for (int co = 0; co < C2_; ++co) { A0[co] = 0.f; A1[co] = 0.f; }

#pragma unroll 1
  for (int g = 0; g < 2; ++g) {
    if (g) __syncthreads();   // previous phase B done before overwriting x1
    // Phase A: conv1+BN1+relu for channels g*5..g*5+4, from cached windows
#pragma unroll 1
    for (int cl = 0; cl < 5; ++cl) {
      const int c = g * 5 + cl;
      const float bc = b1g[c];
      const float sc = ac1[c], sh = ac1[C1_ + c];
      {
        float a0 = bc, a1 = bc;
#pragma unroll
        for (int m = 0; m < 8; ++m) {
          float w = w1g[c * K1_ + 2 * m];
          a0 += w * wEa[m]; a1 += w * wEa[m + 1];
        }
#pragma unroll
        for (int m = 0; m < 7; ++m) {
          float w = w1g[c * K1_ + 2 * m + 1];
          a0 += w * wOa[m]; a1 += w * wOa[m + 1];
        }
        x1E[cl * X1ST_ + tid] = fmaxf(sc * a0 + sh, 0.f);
        x1O[cl * X1ST_ + tid] = fmaxf(sc * a1 + sh, 0.f);
      }
      if (act1) {
        float a0 = bc, a1 = bc;
#pragma unroll
        for (int m = 0; m < 8; ++m) {
          float w = w1g[c * K1_ + 2 * m];
          a0 += w * wEb[m]; a1 += w * wEb[m + 1];
        }
#pragma unroll
        for (int m = 0; m < 7; ++m) {
          float w = w1g[c * K1_ + 2 * m + 1];
          a0 += w * wOb[m]; a1 += w * wOb[m + 1];
        }
        x1E[cl * X1ST_ + j1] = fmaxf(sc * a0 + sh, 0.f);
        if (two1) x1O[cl * X1ST_ + j1] = fmaxf(sc * a1 + sh, 0.f);
      }
    }
    __syncthreads();

    // Phase B partial: accumulate these 5 input channels for outputs 2t,2t+1
    if (tid < 175) {
#pragma unroll 1
      for (int cl = 0; cl < 5; ++cl) {
        const int ci = g * 5 + cl;
        float xE[9], xO[8];
        {
          const float* pE = &x1E[cl * X1ST_ + 2 * tid];
          float2 e0 = *(const float2*)(pE + 0);
          float2 e1 = *(const float2*)(pE + 2);
          float2 e2 = *(const float2*)(pE + 4);
          float2 e3 = *(const float2*)(pE + 6);
          xE[0] = e0.x; xE[1] = e0.y; xE[2] = e1.x; xE[3] = e1.y;
          xE[4] = e2.x; xE[5] = e2.y; xE[6] = e3.x; xE[7] = e3.y;
          xE[8] = pE[8];
          const float* pO = &x1O[cl * X1ST_ + 2 * tid];
          float2 o0 = *(const float2*)(pO + 0);
          float2 o1 = *(const float2*)(pO + 2);
          float2 o2 = *(const float2*)(pO + 4);
          float2 o3 = *(const float2*)(pO + 6);
          xO[0] = o0.x; xO[1] = o0.y; xO[2] = o1.x; xO[3] = o1.y;
          xO[4] = o2.x; xO[5] = o2.y; xO[6] = o3.x; xO[7] = o3.y;
        }
#pragma unroll
        for (int co = 0; co < C2_; ++co) {
#pragma unroll
          for (int m = 0; m < 8; ++m) {
            float w = w2g[(co * C1_ + ci) * K1_ + 2 * m];
            A0[co] += w * xE[m]; A1[co] += w * xE[m + 1];
          }
#pragma unroll
          for (int m = 0; m < 7; ++m) {
            float w = w2g[(co * C1_ + ci) * K1_ + 2 * m + 1];
            A0[co] += w * xO[m]; A1[co] += w * xO[m + 1];
          }
        }
      }
    }
  }

  float t1[C2_], t2[C2_];
#pragma unroll
  for (int co = 0; co < C2_; ++co) { t1[co] = 0.f; t2[co] = 0.f; }
  if (tid < 175) {
#pragma unroll
    for (int co = 0; co < C2_; ++co) {
      float o0 = A0[co] + b2g[co];
      float o1 = A1[co] + b2g[co];
      *(float2*)&x2g[b * (C2_ * L2_) + co * L2_ + 2 * tid] = make_float2(o0, o1);
      t1[co] = o0 + o1; t2[co] = o0 * o0 + o1 * o1;
    }
  }
#pragma unroll
  for (int co = 0; co < C2_; ++co) {
#pragma unroll
    for (int off = 32; off > 0; off >>= 1) {
      t1[co] += __shfl_down(t1[co], off, 64);
      t2[co] += __shfl_down(t2[co], off, 64);
    }
  }
  if ((tid & 63) == 0) {
#pragma unroll
    for (int co = 0; co < C2_; ++co) {
      red[wid][co * 2 + 0] = t1[co];
      red[wid][co * 2 + 1] = t2[co];
    }
  }
  __syncthreads();
  if (tid < C2_ * 2) {
    float S = red[0][tid] + red[1][tid] + red[2][tid];
    part2[b * (C2_ * 2) + tid] = S;   // (b*C2 + c)*2 + s
  }
}

// ---------------- Kernel 6: fused BN2+relu+maxpool5, lin_gene, concat, mlin (2-way split) + tanh, mconv1, stats ----------------
__global__ __launch_bounds__(256) void k_gene(
    const float* __restrict__ x2g, const float* __restrict__ ac2,
    const int* __restrict__ did, const float* __restrict__ compound,
    const float* __restrict__ lgwg, const float* __restrict__ lgbg,
    const float* __restrict__ mwg, const float* __restrict__ mbg,
    const float* __restrict__ mw1g, const float* __restrict__ mb1g,
    float* __restrict__ mraw1, float* __restrict__ partm1)
{
  const int b = blockIdx.x, tid = threadIdx.x;
  __shared__ float pooled[C2_ * LP_];
  __shared__ float lgw[LP_ * LO_];
  __shared__ float cat[CAT_];
  __shared__ float mv[M_];
  __shared__ float mvp[2][M_];
  __shared__ float red1[C2_ * LM1_], red2[C2_ * LM1_];
  __shared__ float a2s[C2_], c2s[C2_];
  if (tid < C2_) { a2s[tid] = ac2[tid]; c2s[tid] = ac2[C2_ + tid]; }
  for (int i = tid; i < LP_ * LO_; i += 256) lgw[i] = lgwg[i];
  __syncthreads();
  for (int i = tid; i < C2_ * LP_; i += 256) {
    int c = i / LP_, p = i - c * LP_;
    const float* xr = x2g + (size_t)b * (C2_ * L2_) + c * L2_ + 5 * p;
    float aa = a2s[c], cc = c2s[c];
    float m = aa * xr[0] + cc;
    m = fmaxf(m, aa * xr[1] + cc);
    m = fmaxf(m, aa * xr[2] + cc);
    m = fmaxf(m, aa * xr[3] + cc);
    m = fmaxf(m, aa * xr[4] + cc);
    pooled[i] = fmaxf(m, 0.f);
  }
  __syncthreads();
  if (tid < 160) {
    int c = tid >> 5, o = tid & 31;
    float a = lgbg[o];
    for (int l = 0; l < LP_; ++l) a += pooled[c * LP_ + l] * lgw[l * LO_ + o];
    cat[tid] = fmaxf(a, 0.f);
  } else if (tid < CAT_) {
    cat[tid] = compound[did[b] * D_ + (tid - 160)];
  }
  __syncthreads();
  if (tid < 200) {
    int half = tid / 100, o = tid - half * 100;
    float a = 0.f;
    int i0 = half * 105;
    for (int i = i0; i < i0 + 105; ++i) a += cat[i] * mwg[i * M_ + o];
    mvp[half][o] = a;
  }
  __syncthreads();
  if (tid < M_) mv[tid] = tanhf(mvp[0][tid] + mvp[1][tid] + mbg[tid]);
  __syncthreads();
  if (tid < C2_ * LM1_) {
    int c = tid / LM1_, t = tid - c * LM1_;
    float a = mb1g[c];
#pragma unroll
    for (int k = 0; k < 10; ++k) a += mw1g[c * 10 + k] * mv[2 * t + k];
    mraw1[b * (C2_ * LM1_) + c * LM1_ + t] = a;
    red1[tid] = a;
    red2[tid] = a * a;
  }
  __syncthreads();
  if (tid < C2_) {
    float S1 = 0.f, S2 = 0.f;
    for (int j = 0; j < LM1_; ++j) { S1 += red1[tid * LM1_ + j]; S2 += red2[tid * LM1_ + j]; }
    partm1[(b * C2_ + tid) * 2 + 0] = S1;
    partm1[(b * C2_ + tid) * 2 + 1] = S2;
  }
}

// ---------------- Kernel 8: mbn1+maxpool3, mconv2, stats ----------------
__global__ __launch_bounds__(256) void k_mhead2(
    const float* __restrict__ mraw1, const float* __restrict__ acm1,
    const float* __restrict__ mw2g, const float* __restrict__ mb2g,
    float* __restrict__ mraw2, float* __restrict__ partm2)
{
  const int tid = threadIdx.x;
  const int b = blockIdx.x * 256 + tid;
  __shared__ float w2[C2_ * C2_ * 10];
  __shared__ float a1[C2_], c1[C2_], b2s[C2_];
  __shared__ float rw1[C2_][4], rw2[C2_][4];
  if (tid < C2_ * C2_ * 10) w2[tid] = mw2g[tid];
  if (tid < C2_) { a1[tid] = acm1[tid]; c1[tid] = acm1[C2_ + tid]; b2s[tid] = mb2g[tid]; }
  __syncthreads();
  float p[C2_ * PM1_];
  const float* row = mraw1 + (size_t)b * (C2_ * LM1_);
#pragma unroll
  for (int c = 0; c < C2_; ++c) {
    float ac = a1[c], cc = c1[c];
#pragma unroll
    for (int q = 0; q < PM1_; ++q) {
      float m = ac * row[c * LM1_ + 3 * q] + cc;
      m = fmaxf(m, ac * row[c * LM1_ + 3 * q + 1] + cc);
      m = fmaxf(m, ac * row[c * LM1_ + 3 * q + 2] + cc);
      p[c * PM1_ + q] = m;
    }
  }
#pragma unroll
  for (int co = 0; co < C2_; ++co) {
    float t1 = 0.f, t2 = 0.f;
#pragma unroll
    for (int l = 0; l < LM2_; ++l) {
      float a = b2s[co];
#pragma unroll
      for (int ci = 0; ci < C2_; ++ci)
#pragma unroll
        for (int k = 0; k < 10; ++k)
          a += w2[(co * C2_ + ci) * 10 + k] * p[ci * PM1_ + 2 * l + k];
      mraw2[b * (C2_ * LM2_) + co * LM2_ + l] = a;
      t1 += a; t2 += a * a;
    }
#pragma unroll
    for (int off = 32; off > 0; off >>= 1) {
      t1 += __shfl_down(t1, off, 64);
      t2 += __shfl_down(t2, off, 64);
    }
    if ((tid & 63) == 0) { rw1[co][tid >> 6] = t1; rw2[co][tid >> 6] = t2; }
  }
  __syncthreads();
  if (tid < C2_ * 2) {
    int co = tid >> 1, s = tid & 1;
    float S = 0.f;
#pragma unroll
    for (int w = 0; w < 4; ++w) S += (s ? rw2[co][w] : rw1[co][w]);
    partm2[blockIdx.x * (C2_ * 2) + tid] = S;
  }
}

// ---------------- Kernel 10: mbn2 + maxpool3 + output layer ----------------
__global__ __launch_bounds__(256) void k_final(
    const float* __restrict__ mraw2, const float* __restrict__ acm2,
    const float* __restrict__ owg, const float* __restrict__ obg,
    float* __restrict__ out)
{
  const int b = blockIdx.x * 256 + threadIdx.x;
  float y = obg[0];
#pragma unroll
  for (int c = 0; c < C2_; ++c) {
    float a = acm2[c], cc = acm2[C2_ + c];
    float m = a * mraw2[b * 15 + c * 3 + 0] + cc;
    m = fmaxf(m, a * mraw2[b * 15 + c * 3 + 1] + cc);
    m = fmaxf(m, a * mraw2[b * 15 + c * 3 + 2] + cc);
    y += owg[c] * m;
  }
  out[b] = y;
}

extern "C" void kernel_launch(void* const* d_in, const int* in_sizes, int n_in,
                              void* d_out, int out_size, void* d_ws, size_t ws_size,
                              hipStream_t stream) {
  (void)in_sizes; (void)n_in; (void)out_size; (void)ws_size;
  const float* rma   = (const float*)d_in[0];
  const float* varr  = (const float*)d_in[1];
  const int*   did   = (const int*)d_in[2];
  const float* fw    = (const float*)d_in[3];
  const float* sim   = (const float*)d_in[4];
  const float* embed = (const float*)d_in[5];
  const float* gW    = (const float*)d_in[6];
  const float* gb    = (const float*)d_in[7];
  const int*   fp    = (const int*)d_in[8];
  const float* adj   = (const float*)d_in[9];
  const float* w1g   = (const float*)d_in[10];
  const float* b1g   = (const float*)d_in[11];
  const float* bn1g  = (const float*)d_in[12];
  const float* bn1b  = (const float*)d_in[13];
  const float* w2g   = (const float*)d_in[14];
  const float* b2g   = (const float*)d_in[15];
  const float* bn2g  = (const float*)d_in[16];
  const float* bn2b  = (const float*)d_in[17];
  const float* lgwg  = (const float*)d_in[18];
  const float* lgbg  = (const float*)d_in[19];
  const float* mwg   = (const float*)d_in[20];
  const float* mbg   = (const float*)d_in[21];
  const float* mw1g  = (const float*)d_in[22];
  const float* mb1g  = (const float*)d_in[23];
  const float* mbn1g = (const float*)d_in[24];
  const float* mbn1b = (const float*)d_in[25];
  const float* mw2g  = (const float*)d_in[26];
  const float* mb2g  = (const float*)d_in[27];
  const float* mbn2g = (const float*)d_in[28];
  const float* mbn2b = (const float*)d_in[29];
  const float* owg   = (const float*)d_in[30];
  const float* obg   = (const float*)d_in[31];
  float* out = (float*)d_out;

  float* ws = (float*)d_ws;
  size_t o = 0;
  float* P        = ws + o; o += (size_t)DR_ * NG_;
  float* compound = ws + o; o += (size_t)DR_ * D_;
  float* comg     = ws + o; o += (size_t)B_ * NG_;
  float* part1    = ws + o; o += (size_t)B_ * C1_ * 2;
  float* ac1      = ws + o; o += 2 * C1_;
  float* x2g      = ws + o; o += (size_t)B_ * C2_ * L2_;
  float* part2    = ws + o; o += (size_t)B_ * C2_ * 2;
  float* ac2      = ws + o; o += 2 * C2_;
  float* mraw1    = ws + o; o += (size_t)B_ * C2_ * LM1_;
  float* partm1   = ws + o; o += (size_t)B_ * C2_ * 2;
  float* acm1     = ws + o; o += 2 * C2_;
  float* mraw2    = ws + o; o += (size_t)B_ * C2_ * LM2_;
  float* partm2   = ws + o; o += 16 * C2_ * 2;
  float* acm2     = ws + o; o += 2 * C2_;

  hipLaunchKernelGGL(k_fuse, dim3(DR_ / 2, 6), dim3(256), 0, stream, fw, sim, P);
  hipLaunchKernelGGL(k_gnn, dim3(DR_), dim3(256), 0, stream,
                     embed, gW, gb, fp, adj, compound);
  hipLaunchKernelGGL(k_conv1, dim3(B_), dim3(384), 0, stream,
                     rma, varr, did, P, w1g, b1g, comg, part1);
  hipLaunchKernelGGL(k_bnfin, dim3(C1_), dim3(256), 0, stream,
                     part1, B_, C1_, (float)B_ * (float)L1_, bn1g, bn1b, ac1);
  hipLaunchKernelGGL(k_conv2, dim3(B_), dim3(192), 0, stream,
                     comg, w1g, b1g, ac1, w2g, b2g, x2g, part2);
  hipLaunchKernelGGL(k_bnfin, dim3(C2_), dim3(256), 0, stream,
                     part2, B_, C2_, (float)B_ * (float)L2_, bn2g, bn2b, ac2);
  hipLaunchKernelGGL(k_gene, dim3(B_), dim3(256), 0, stream,
                     x2g, ac2, did, compound, lgwg, lgbg, mwg, mbg, mw1g, mb1g,
                     mraw1, partm1);
  hipLaunchKernelGGL(k_bnfin, dim3(C2_), dim3(256), 0, stream,
                     partm1, B_, C2_, (float)B_ * (float)LM1_, mbn1g, mbn1b, acm1);
  hipLaunchKernelGGL(k_mhead2, dim3(16), dim3(256), 0, stream,
                     mraw1, acm1, mw2g, mb2g, mraw2, partm2);
  hipLaunchKernelGGL(k_bnfin, dim3(C2_), dim3(256), 0, stream,
                     partm2, 16, C2_, (float)B_ * (float)LM2_, mbn2g, mbn2b, acm2);
  hipLaunchKernelGGL(k_final, dim3(16), dim3(256), 0, stream,
                     mraw2, acm2, owg, obg, out);
}

// Round 17
// 234.825 us; speedup vs baseline: 2.2749x; 1.0146x over previous
//
#include <hip/hip_runtime.h>

#define EPS 1e-5f

#define B_   4096
#define NG_  1440
#define DR_  222
#define D_   50
#define NA_  64
#define LG_  3
#define L1_  713
#define C1_  10
#define K1_  15
#define L2_  350
#define C2_  5
#define LP_  70
#define LO_  32
#define CAT_ 210
#define M_   100
#define LM1_ 46
#define PM1_ 15
#define LM2_ 3

#define X1ST_ 360     // x1E/x1O row stride (>= 357)

// ---------------- Kernel 1a: P = sim @ clip(fw,0,1) ----------------
__global__ __launch_bounds__(256) void k_fuse(
    const float* __restrict__ fw, const float* __restrict__ sim,
    float* __restrict__ P)
{
  const int d0 = blockIdx.x * 2;
  const int g = blockIdx.y * 256 + threadIdx.x;
  const int tid = threadIdx.x;
  __shared__ float s0[DR_], s1[DR_];
  for (int r = tid; r < DR_; r += 256) {
    s0[r] = sim[d0 * DR_ + r];
    s1[r] = sim[(d0 + 1) * DR_ + r];
  }
  __syncthreads();
  if (g >= NG_) return;
  float a0 = 0.f, a1 = 0.f;
#pragma unroll 6
  for (int r = 0; r < DR_; ++r) {
    float w = fw[r * NG_ + g];
    w = fminf(fmaxf(w, 0.f), 1.f);
    a0 += s0[r] * w;
    a1 += s1[r] * w;
  }
  P[d0 * NG_ + g] = a0;
  P[(d0 + 1) * NG_ + g] = a1;
}

// ---------------- Kernel 1b: GNN, lane=node, xs & A register-resident ----------------
__global__ __launch_bounds__(256) void k_gnn(
    const float* __restrict__ embed, const float* __restrict__ gW,
    const float* __restrict__ gb, const int* __restrict__ fp,
    const float* __restrict__ adj, float* __restrict__ compound)
{
  const int d = blockIdx.x;
  const int tid = threadIdx.x;
  const int wid = tid >> 6, lane = tid & 63;
  __shared__ __align__(16) float WT[D_ * 52];
  __shared__ __align__(16) float hsl[NA_ * 52];
  __shared__ float xsl[NA_ * 53];
  __shared__ float bl[D_];
  __shared__ int fps[NA_];

  if (tid < NA_) fps[tid] = fp[d * NA_ + tid];
  if (wid == 0) { hsl[lane * 52 + 50] = 0.f; hsl[lane * 52 + 51] = 0.f; }
  __syncthreads();

  float xs[52];
  const float* erow = embed + (size_t)fps[lane] * D_;
#pragma unroll
  for (int j = 0; j < D_; ++j) xs[j] = erow[j];
  xs[50] = 0.f; xs[51] = 0.f;
  float Ar[NA_];
  const float* arow = adj + (size_t)d * NA_ * NA_ + lane * NA_;
#pragma unroll
  for (int j = 0; j < NA_; ++j) Ar[j] = arow[j];

  const int e0 = (wid < 2) ? wid * 13 : 26 + (wid - 2) * 12;
  const int ecnt = (wid < 2) ? 13 : 12;

  for (int layer = 0; layer < LG_; ++layer) {
    const float* Wg = gW + layer * D_ * D_;
    for (int i = tid; i < D_ * 52; i += 256) {
      int e = i / 52, dd = i - e * 52;
      WT[i] = (dd < D_) ? Wg[dd * D_ + e] : 0.f;
    }
    if (tid < D_) bl[tid] = gb[layer * D_ + tid];
    __syncthreads();

    for (int ei = 0; ei < ecnt; ++ei) {
      int e = e0 + ei;
      float c0 = bl[e], c1 = 0.f, c2 = 0.f, c3 = 0.f;
#pragma unroll
      for (int c = 0; c < 13; ++c) {
        float4 wv = *(const float4*)&WT[e * 52 + 4 * c];
        c0 += xs[4 * c + 0] * wv.x;
        c1 += xs[4 * c + 1] * wv.y;
        c2 += xs[4 * c + 2] * wv.z;
        c3 += xs[4 * c + 3] * wv.w;
      }
      hsl[lane * 52 + e] = fmaxf((c0 + c1) + (c2 + c3), 0.f);
    }
    __syncthreads();

    for (int c = wid; c < 13; c += 4) {
      float a0 = 0.f, a1 = 0.f, a2 = 0.f, a3 = 0.f;
#pragma unroll
      for (int m = 0; m < NA_; ++m) {
        float4 hv = *(const float4*)&hsl[m * 52 + 4 * c];
        float am = Ar[m];
        a0 += am * hv.x; a1 += am * hv.y; a2 += am * hv.z; a3 += am * hv.w;
      }
      int dd = 4 * c;
      xsl[lane * 53 + dd + 0] = xs[dd + 0] + a0;
      xsl[lane * 53 + dd + 1] = xs[dd + 1] + a1;
      if (dd + 2 < D_) {
        xsl[lane * 53 + dd + 2] = xs[dd + 2] + a2;
        xsl[lane * 53 + dd + 3] = xs[dd + 3] + a3;
      }
    }
    __syncthreads();
#pragma unroll
    for (int j = 0; j < D_; ++j) xs[j] = xsl[lane * 53 + j];
    __syncthreads();
  }

  if (wid == 0 && lane < D_) {
    float s = 0.f;
    for (int n = 0; n < NA_; ++n) s += xsl[n * 53 + lane];
    compound[d * D_ + lane] = s * (1.f / NA_);
  }
}

// ---------------- Kernel 2: com (register-direct) + comg store + conv1 stats ----------------
__global__ __launch_bounds__(384, 4) void k_conv1(
    const float* __restrict__ rma, const float* __restrict__ varr,
    const int* __restrict__ did, const float* __restrict__ P,
    const float* __restrict__ w1g, const float* __restrict__ b1g,
    float* __restrict__ comg, float* __restrict__ part1)
{
  const int b = blockIdx.x, tid = threadIdx.x;
  const int wid = tid >> 6;
  __shared__ float red[6][C1_ * 2];
  const int dd = did[b];
  const float* rb = rma  + (size_t)b * NG_ + 4 * tid;
  const float* vb = varr + (size_t)b * NG_ + 4 * tid;
  const float* pp = P    + (size_t)dd * NG_ + 4 * tid;

  float s1[C1_], s2[C1_];
#pragma unroll
  for (int c = 0; c < C1_; ++c) { s1[c] = 0.f; s2[c] = 0.f; }

  if (tid < 357) {
    float4 r0 = *(const float4*)(rb + 0),  r1 = *(const float4*)(rb + 4);
    float4 r2 = *(const float4*)(rb + 8),  r3 = *(const float4*)(rb + 12);
    float4 v0 = *(const float4*)(vb + 0),  v1 = *(const float4*)(vb + 4);
    float4 v2 = *(const float4*)(vb + 8),  v3 = *(const float4*)(vb + 12);
    float4 p0 = *(const float4*)(pp + 0),  p1 = *(const float4*)(pp + 4);
    float4 p2 = *(const float4*)(pp + 8),  p3 = *(const float4*)(pp + 12);
    const bool two = (tid < 356);
    float wE[9], wO[8];
    wE[0] = r0.x + p0.x * v0.x;  wO[0] = r0.y + p0.y * v0.y;
    wE[1] = r0.z + p0.z * v0.z;  wO[1] = r0.w + p0.w * v0.w;
    wE[2] = r1.x + p1.x * v1.x;  wO[2] = r1.y + p1.y * v1.y;
    wE[3] = r1.z + p1.z * v1.z;  wO[3] = r1.w + p1.w * v1.w;
    wE[4] = r2.x + p2.x * v2.x;  wO[4] = r2.y + p2.y * v2.y;
    wE[5] = r2.z + p2.z * v2.z;  wO[5] = r2.w + p2.w * v2.w;
    wE[6] = r3.x + p3.x * v3.x;  wO[6] = r3.y + p3.y * v3.y;
    wE[7] = r3.z + p3.z * v3.z;  wO[7] = r3.w + p3.w * v3.w;
    wE[8] = two ? (rb[16] + pp[16] * vb[16]) : 0.f;
    *(float4*)&comg[(size_t)b * NG_ + 4 * tid] =
        make_float4(wE[0], wO[0], wE[1], wO[1]);
#pragma unroll
    for (int c = 0; c < C1_; ++c) {
      float a0 = b1g[c], a1 = a0;
#pragma unroll
      for (int m = 0; m < 8; ++m) {
        float w = w1g[c * K1_ + 2 * m];
        a0 += w * wE[m]; a1 += w * wE[m + 1];
      }
#pragma unroll
      for (int m = 0; m < 7; ++m) {
        float w = w1g[c * K1_ + 2 * m + 1];
        a0 += w * wO[m]; a1 += w * wO[m + 1];
      }
      s1[c] = a0; s2[c] = a0 * a0;
      if (two) { s1[c] += a1; s2[c] += a1 * a1; }
    }
  } else if (tid < 360) {
    float4 r0 = *(const float4*)(rb);
    float4 v0 = *(const float4*)(vb);
    float4 p0 = *(const float4*)(pp);
    *(float4*)&comg[(size_t)b * NG_ + 4 * tid] =
        make_float4(r0.x + p0.x * v0.x, r0.y + p0.y * v0.y,
                    r0.z + p0.z * v0.z, r0.w + p0.w * v0.w);
  }

#pragma unroll
  for (int c = 0; c < C1_; ++c) {
#pragma unroll
    for (int off = 32; off > 0; off >>= 1) {
      s1[c] += __shfl_down(s1[c], off, 64);
      s2[c] += __shfl_down(s2[c], off, 64);
    }
  }
  if ((tid & 63) == 0) {
#pragma unroll
    for (int c = 0; c < C1_; ++c) {
      red[wid][c * 2 + 0] = s1[c];
      red[wid][c * 2 + 1] = s2[c];
    }
  }
  __syncthreads();
  if (tid < C1_ * 2) {
    float S = 0.f;
#pragma unroll
    for (int w = 0; w < 6; ++w) S += red[w][tid];
    part1[b * (C1_ * 2) + tid] = S;   // (b*C1 + c)*2 + s
  }
}

// ---------------- BN finalize ----------------
__global__ __launch_bounds__(256) void k_bnfin(
    const float* __restrict__ part, int nblk, int C, float N,
    const float* __restrict__ g, const float* __restrict__ bta,
    float* __restrict__ ac)
{
  const int c = blockIdx.x, tid = threadIdx.x;
  float s1 = 0.f, s2 = 0.f;
  for (int j = tid; j < nblk; j += 256) {
    s1 += part[(j * C + c) * 2 + 0];
    s2 += part[(j * C + c) * 2 + 1];
  }
#pragma unroll
  for (int off = 32; off > 0; off >>= 1) {
    s1 += __shfl_down(s1, off, 64);
    s2 += __shfl_down(s2, off, 64);
  }
  __shared__ float r1[4], r2[4];
  int w = tid >> 6;
  if ((tid & 63) == 0) { r1[w] = s1; r2[w] = s2; }
  __syncthreads();
  if (tid == 0) {
    float S1 = r1[0] + r1[1] + r1[2] + r1[3];
    float S2 = r2[0] + r2[1] + r2[2] + r2[3];
    float mean = S1 / N;
    float v = S2 / N - mean * mean;
    float a = g[c] * rsqrtf(v + EPS);
    ac[c] = a;
    ac[C + c] = bta[c] - mean * a;
  }
}

// ---------------- Kernel 4: channel-split half-LDS double-pass (R13 structure) + float2 phase-B reads ----------------
// Windows are RE-READ from global each g pass (L1/L2-served) — caching them in
// registers across the barriered passes spilled to scratch (R16: +135 MB HBM).
__global__ __launch_bounds__(192, 6) void k_conv2(
    const float* __restrict__ comg, const float* __restrict__ w1g,
    const float* __restrict__ b1g, const float* __restrict__ ac1,
    const float* __restrict__ w2g, const float* __restrict__ b2g,
    float* __restrict__ x2g, float* __restrict__ part2)
{
  const int b = blockIdx.x, tid = threadIdx.x;
  const int wid = tid >> 6;                 // 0..2
  __shared__ __align__(8) float x1E[5 * X1ST_], x1O[5 * X1ST_];
  __shared__ float red[3][C2_ * 2];

  float A0[C2_], A1[C2_];
#pragma unroll
  for (int co = 0; co < C2_; ++co) { A0[co] = 0.f; A1[co] = 0.f; }

#pragma unroll 1
  for (int g = 0; g < 2; ++g) {
    if (g) __syncthreads();   // previous phase B done before overwriting x1
    // Phase A: conv1+BN1+relu for channels g*5..g*5+4; window direct from global
#pragma unroll 1
    for (int j = tid; j < 357; j += 192) {
      const float* base = comg + (size_t)b * NG_ + 4 * j;
      float4 v0 = *(const float4*)(base + 0);
      float4 v1 = *(const float4*)(base + 4);
      float4 v2 = *(const float4*)(base + 8);
      float4 v3 = *(const float4*)(base + 12);
      const bool two = (j < 356);
      float wE[9], wO[8];
      wE[0] = v0.x; wE[1] = v0.z; wE[2] = v1.x; wE[3] = v1.z;
      wE[4] = v2.x; wE[5] = v2.z; wE[6] = v3.x; wE[7] = v3.z;
      wE[8] = two ? base[16] : 0.f;
      wO[0] = v0.y; wO[1] = v0.w; wO[2] = v1.y; wO[3] = v1.w;
      wO[4] = v2.y; wO[5] = v2.w; wO[6] = v3.y; wO[7] = v3.w;
#pragma unroll 1
      for (int cl = 0; cl < 5; ++cl) {
        const int c = g * 5 + cl;
        float a0 = b1g[c], a1 = a0;
#pragma unroll
        for (int m = 0; m < 8; ++m) {
          float w = w1g[c * K1_ + 2 * m];
          a0 += w * wE[m]; a1 += w * wE[m + 1];
        }
#pragma unroll
        for (int m = 0; m < 7; ++m) {
          float w = w1g[c * K1_ + 2 * m + 1];
          a0 += w * wO[m]; a1 += w * wO[m + 1];
        }
        float sc = ac1[c], sh = ac1[C1_ + c];
        x1E[cl * X1ST_ + j] = fmaxf(sc * a0 + sh, 0.f);
        if (two) x1O[cl * X1ST_ + j] = fmaxf(sc * a1 + sh, 0.f);
      }
    }
    __syncthreads();

    // Phase B partial: accumulate these 5 input channels for outputs 2t,2t+1
    if (tid < 175) {
#pragma unroll 1
      for (int cl = 0; cl < 5; ++cl) {
        const int ci = g * 5 + cl;
        float xE[9], xO[8];
        {
          const float* pE = &x1E[cl * X1ST_ + 2 * tid];
          float2 e0 = *(const float2*)(pE + 0);
          float2 e1 = *(const float2*)(pE + 2);
          float2 e2 = *(const float2*)(pE + 4);
          float2 e3 = *(const float2*)(pE + 6);
          xE[0] = e0.x; xE[1] = e0.y; xE[2] = e1.x; xE[3] = e1.y;
          xE[4] = e2.x; xE[5] = e2.y; xE[6] = e3.x; xE[7] = e3.y;
          xE[8] = pE[8];
          const float* pO = &x1O[cl * X1ST_ + 2 * tid];
          float2 o0 = *(const float2*)(pO + 0);
          float2 o1 = *(const float2*)(pO + 2);
          float2 o2 = *(const float2*)(pO + 4);
          float2 o3 = *(const float2*)(pO + 6);
          xO[0] = o0.x; xO[1] = o0.y; xO[2] = o1.x; xO[3] = o1.y;
          xO[4] = o2.x; xO[5] = o2.y; xO[6] = o3.x; xO[7] = o3.y;
        }
#pragma unroll
        for (int co = 0; co < C2_; ++co) {
#pragma unroll
          for (int m = 0; m < 8; ++m) {
            float w = w2g[(co * C1_ + ci) * K1_ + 2 * m];
            A0[co] += w * xE[m]; A1[co] += w * xE[m + 1];
          }
#pragma unroll
          for (int m = 0; m < 7; ++m) {
            float w = w2g[(co * C1_ + ci) * K1_ + 2 * m + 1];
            A0[co] += w * xO[m]; A1[co] += w * xO[m + 1];
          }
        }
      }
    }
  }

  float t1[C2_], t2[C2_];
#pragma unroll
  for (int co = 0; co < C2_; ++co) { t1[co] = 0.f; t2[co] = 0.f; }
  if (tid < 175) {
#pragma unroll
    for (int co = 0; co < C2_; ++co) {
      float o0 = A0[co] + b2g[co];
      float o1 = A1[co] + b2g[co];
      *(float2*)&x2g[b * (C2_ * L2_) + co * L2_ + 2 * tid] = make_float2(o0, o1);
      t1[co] = o0 + o1; t2[co] = o0 * o0 + o1 * o1;
    }
  }
#pragma unroll
  for (int co = 0; co < C2_; ++co) {
#pragma unroll
    for (int off = 32; off > 0; off >>= 1) {
      t1[co] += __shfl_down(t1[co], off, 64);
      t2[co] += __shfl_down(t2[co], off, 64);
    }
  }
  if ((tid & 63) == 0) {
#pragma unroll
    for (int co = 0; co < C2_; ++co) {
      red[wid][co * 2 + 0] = t1[co];
      red[wid][co * 2 + 1] = t2[co];
    }
  }
  __syncthreads();
  if (tid < C2_ * 2) {
    float S = red[0][tid] + red[1][tid] + red[2][tid];
    part2[b * (C2_ * 2) + tid] = S;   // (b*C2 + c)*2 + s
  }
}

// ---------------- Kernel 6: fused BN2+relu+maxpool5, lin_gene, concat, mlin (2-way split) + tanh, mconv1, stats ----------------
__global__ __launch_bounds__(256) void k_gene(
    const float* __restrict__ x2g, const float* __restrict__ ac2,
    const int* __restrict__ did, const float* __restrict__ compound,
    const float* __restrict__ lgwg, const float* __restrict__ lgbg,
    const float* __restrict__ mwg, const float* __restrict__ mbg,
    const float* __restrict__ mw1g, const float* __restrict__ mb1g,
    float* __restrict__ mraw1, float* __restrict__ partm1)
{
  const int b = blockIdx.x, tid = threadIdx.x;
  __shared__ float pooled[C2_ * LP_];
  __shared__ float lgw[LP_ * LO_];
  __shared__ float cat[CAT_];
  __shared__ float mv[M_];
  __shared__ float mvp[2][M_];
  __shared__ float red1[C2_ * LM1_], red2[C2_ * LM1_];
  __shared__ float a2s[C2_], c2s[C2_];
  if (tid < C2_) { a2s[tid] = ac2[tid]; c2s[tid] = ac2[C2_ + tid]; }
  for (int i = tid; i < LP_ * LO_; i += 256) lgw[i] = lgwg[i];
  __syncthreads();
  for (int i = tid; i < C2_ * LP_; i += 256) {
    int c = i / LP_, p = i - c * LP_;
    const float* xr = x2g + (size_t)b * (C2_ * L2_) + c * L2_ + 5 * p;
    float aa = a2s[c], cc = c2s[c];
    float m = aa * xr[0] + cc;
    m = fmaxf(m, aa * xr[1] + cc);
    m = fmaxf(m, aa * xr[2] + cc);
    m = fmaxf(m, aa * xr[3] + cc);
    m = fmaxf(m, aa * xr[4] + cc);
    pooled[i] = fmaxf(m, 0.f);
  }
  __syncthreads();
  if (tid < 160) {
    int c = tid >> 5, o = tid & 31;
    float a = lgbg[o];
    for (int l = 0; l < LP_; ++l) a += pooled[c * LP_ + l] * lgw[l * LO_ + o];
    cat[tid] = fmaxf(a, 0.f);
  } else if (tid < CAT_) {
    cat[tid] = compound[did[b] * D_ + (tid - 160)];
  }
  __syncthreads();
  if (tid < 200) {
    int half = tid / 100, o = tid - half * 100;
    float a = 0.f;
    int i0 = half * 105;
    for (int i = i0; i < i0 + 105; ++i) a += cat[i] * mwg[i * M_ + o];
    mvp[half][o] = a;
  }
  __syncthreads();
  if (tid < M_) mv[tid] = tanhf(mvp[0][tid] + mvp[1][tid] + mbg[tid]);
  __syncthreads();
  if (tid < C2_ * LM1_) {
    int c = tid / LM1_, t = tid - c * LM1_;
    float a = mb1g[c];
#pragma unroll
    for (int k = 0; k < 10; ++k) a += mw1g[c * 10 + k] * mv[2 * t + k];
    mraw1[b * (C2_ * LM1_) + c * LM1_ + t] = a;
    red1[tid] = a;
    red2[tid] = a * a;
  }
  __syncthreads();
  if (tid < C2_) {
    float S1 = 0.f, S2 = 0.f;
    for (int j = 0; j < LM1_; ++j) { S1 += red1[tid * LM1_ + j]; S2 += red2[tid * LM1_ + j]; }
    partm1[(b * C2_ + tid) * 2 + 0] = S1;
    partm1[(b * C2_ + tid) * 2 + 1] = S2;
  }
}

// ---------------- Kernel 8: mbn1+maxpool3, mconv2, stats ----------------
__global__ __launch_bounds__(256) void k_mhead2(
    const float* __restrict__ mraw1, const float* __restrict__ acm1,
    const float* __restrict__ mw2g, const float* __restrict__ mb2g,
    float* __restrict__ mraw2, float* __restrict__ partm2)
{
  const int tid = threadIdx.x;
  const int b = blockIdx.x * 256 + tid;
  __shared__ float w2[C2_ * C2_ * 10];
  __shared__ float a1[C2_], c1[C2_], b2s[C2_];
  __shared__ float rw1[C2_][4], rw2[C2_][4];
  if (tid < C2_ * C2_ * 10) w2[tid] = mw2g[tid];
  if (tid < C2_) { a1[tid] = acm1[tid]; c1[tid] = acm1[C2_ + tid]; b2s[tid] = mb2g[tid]; }
  __syncthreads();
  float p[C2_ * PM1_];
  const float* row = mraw1 + (size_t)b * (C2_ * LM1_);
#pragma unroll
  for (int c = 0; c < C2_; ++c) {
    float ac = a1[c], cc = c1[c];
#pragma unroll
    for (int q = 0; q < PM1_; ++q) {
      float m = ac * row[c * LM1_ + 3 * q] + cc;
      m = fmaxf(m, ac * row[c * LM1_ + 3 * q + 1] + cc);
      m = fmaxf(m, ac * row[c * LM1_ + 3 * q + 2] + cc);
      p[c * PM1_ + q] = m;
    }
  }
#pragma unroll
  for (int co = 0; co < C2_; ++co) {
    float t1 = 0.f, t2 = 0.f;
#pragma unroll
    for (int l = 0; l < LM2_; ++l) {
      float a = b2s[co];
#pragma unroll
      for (int ci = 0; ci < C2_; ++ci)
#pragma unroll
        for (int k = 0; k < 10; ++k)
          a += w2[(co * C2_ + ci) * 10 + k] * p[ci * PM1_ + 2 * l + k];
      mraw2[b * (C2_ * LM2_) + co * LM2_ + l] = a;
      t1 += a; t2 += a * a;
    }
#pragma unroll
    for (int off = 32; off > 0; off >>= 1) {
      t1 += __shfl_down(t1, off, 64);
      t2 += __shfl_down(t2, off, 64);
    }
    if ((tid & 63) == 0) { rw1[co][tid >> 6] = t1; rw2[co][tid >> 6] = t2; }
  }
  __syncthreads();
  if (tid < C2_ * 2) {
    int co = tid >> 1, s = tid & 1;
    float S = 0.f;
#pragma unroll
    for (int w = 0; w < 4; ++w) S += (s ? rw2[co][w] : rw1[co][w]);
    partm2[blockIdx.x * (C2_ * 2) + tid] = S;
  }
}

// ---------------- Kernel 10: mbn2 + maxpool3 + output layer ----------------
__global__ __launch_bounds__(256) void k_final(
    const float* __restrict__ mraw2, const float* __restrict__ acm2,
    const float* __restrict__ owg, const float* __restrict__ obg,
    float* __restrict__ out)
{
  const int b = blockIdx.x * 256 + threadIdx.x;
  float y = obg[0];
#pragma unroll
  for (int c = 0; c < C2_; ++c) {
    float a = acm2[c], cc = acm2[C2_ + c];
    float m = a * mraw2[b * 15 + c * 3 + 0] + cc;
    m = fmaxf(m, a * mraw2[b * 15 + c * 3 + 1] + cc);
    m = fmaxf(m, a * mraw2[b * 15 + c * 3 + 2] + cc);
    y += owg[c] * m;
  }
  out[b] = y;
}

extern "C" void kernel_launch(void* const* d_in, const int* in_sizes, int n_in,
                              void* d_out, int out_size, void* d_ws, size_t ws_size,
                              hipStream_t stream) {
  (void)in_sizes; (void)n_in; (void)out_size; (void)ws_size;
  const float* rma   = (const float*)d_in[0];
  const float* varr  = (const float*)d_in[1];
  const int*   did   = (const int*)d_in[2];
  const float* fw    = (const float*)d_in[3];
  const float* sim   = (const float*)d_in[4];
  const float* embed = (const float*)d_in[5];
  const float* gW    = (const float*)d_in[6];
  const float* gb    = (const float*)d_in[7];
  const int*   fp    = (const int*)d_in[8];
  const float* adj   = (const float*)d_in[9];
  const float* w1g   = (const float*)d_in[10];
  const float* b1g   = (const float*)d_in[11];
  const float* bn1g  = (const float*)d_in[12];
  const float* bn1b  = (const float*)d_in[13];
  const float* w2g   = (const float*)d_in[14];
  const float* b2g   = (const float*)d_in[15];
  const float* bn2g  = (const float*)d_in[16];
  const float* bn2b  = (const float*)d_in[17];
  const float* lgwg  = (const float*)d_in[18];
  const float* lgbg  = (const float*)d_in[19];
  const float* mwg   = (const float*)d_in[20];
  const float* mbg   = (const float*)d_in[21];
  const float* mw1g  = (const float*)d_in[22];
  const float* mb1g  = (const float*)d_in[23];
  const float* mbn1g = (const float*)d_in[24];
  const float* mbn1b = (const float*)d_in[25];
  const float* mw2g  = (const float*)d_in[26];
  const float* mb2g  = (const float*)d_in[27];
  const float* mbn2g = (const float*)d_in[28];
  const float* mbn2b = (const float*)d_in[29];
  const float* owg   = (const float*)d_in[30];
  const float* obg   = (const float*)d_in[31];
  float* out = (float*)d_out;

  float* ws = (float*)d_ws;
  size_t o = 0;
  float* P        = ws + o; o += (size_t)DR_ * NG_;
  float* compound = ws + o; o += (size_t)DR_ * D_;
  float* comg     = ws + o; o += (size_t)B_ * NG_;
  float* part1    = ws + o; o += (size_t)B_ * C1_ * 2;
  float* ac1      = ws + o; o += 2 * C1_;
  float* x2g      = ws + o; o += (size_t)B_ * C2_ * L2_;
  float* part2    = ws + o; o += (size_t)B_ * C2_ * 2;
  float* ac2      = ws + o; o += 2 * C2_;
  float* mraw1    = ws + o; o += (size_t)B_ * C2_ * LM1_;
  float* partm1   = ws + o; o += (size_t)B_ * C2_ * 2;
  float* acm1     = ws + o; o += 2 * C2_;
  float* mraw2    = ws + o; o += (size_t)B_ * C2_ * LM2_;
  float* partm2   = ws + o; o += 16 * C2_ * 2;
  float* acm2     = ws + o; o += 2 * C2_;

  hipLaunchKernelGGL(k_fuse, dim3(DR_ / 2, 6), dim3(256), 0, stream, fw, sim, P);
  hipLaunchKernelGGL(k_gnn, dim3(DR_), dim3(256), 0, stream,
                     embed, gW, gb, fp, adj, compound);
  hipLaunchKernelGGL(k_conv1, dim3(B_), dim3(384), 0, stream,
                     rma, varr, did, P, w1g, b1g, comg, part1);
  hipLaunchKernelGGL(k_bnfin, dim3(C1_), dim3(256), 0, stream,
                     part1, B_, C1_, (float)B_ * (float)L1_, bn1g, bn1b, ac1);
  hipLaunchKernelGGL(k_conv2, dim3(B_), dim3(192), 0, stream,
                     comg, w1g, b1g, ac1, w2g, b2g, x2g, part2);
  hipLaunchKernelGGL(k_bnfin, dim3(C2_), dim3(256), 0, stream,
                     part2, B_, C2_, (float)B_ * (float)L2_, bn2g, bn2b, ac2);
  hipLaunchKernelGGL(k_gene, dim3(B_), dim3(256), 0, stream,
                     x2g, ac2, did, compound, lgwg, lgbg, mwg, mbg, mw1g, mb1g,
                     mraw1, partm1);
  hipLaunchKernelGGL(k_bnfin, dim3(C2_), dim3(256), 0, stream,
                     partm1, B_, C2_, (float)B_ * (float)LM1_, mbn1g, mbn1b, acm1);
  hipLaunchKernelGGL(k_mhead2, dim3(16), dim3(256), 0, stream,
                     mraw1, acm1, mw2g, mb2g, mraw2, partm2);
  hipLaunchKernelGGL(k_bnfin, dim3(C2_), dim3(256), 0, stream,
                     partm2, 16, C2_, (float)B_ * (float)LM2_, mbn2g, mbn2b, acm2);
  hipLaunchKernelGGL(k_final, dim3(16), dim3(256), 0, stream,
                     mraw2, acm2, owg, obg, out);
}

// Round 18
// 232.996 us; speedup vs baseline: 2.2928x; 1.0078x over previous
//
#include <hip/hip_runtime.h>

#define EPS 1e-5f

#define B_   4096
#define NG_  1440
#define DR_  222
#define D_   50
#define NA_  64
#define LG_  3
#define L1_  713
#define C1_  10
#define K1_  15
#define L2_  350
#define C2_  5
#define LP_  70
#define LO_  32
#define CAT_ 210
#define M_   100
#define LM1_ 46
#define PM1_ 15
#define LM2_ 3

#define X1ST_ 360     // x1E/x1O row stride (>= 357)

// ---------------- Kernel 1a: P = sim @ clip(fw,0,1) ----------------
__global__ __launch_bounds__(256) void k_fuse(
    const float* __restrict__ fw, const float* __restrict__ sim,
    float* __restrict__ P)
{
  const int d0 = blockIdx.x * 2;
  const int g = blockIdx.y * 256 + threadIdx.x;
  const int tid = threadIdx.x;
  __shared__ float s0[DR_], s1[DR_];
  for (int r = tid; r < DR_; r += 256) {
    s0[r] = sim[d0 * DR_ + r];
    s1[r] = sim[(d0 + 1) * DR_ + r];
  }
  __syncthreads();
  if (g >= NG_) return;
  float a0 = 0.f, a1 = 0.f;
#pragma unroll 6
  for (int r = 0; r < DR_; ++r) {
    float w = fw[r * NG_ + g];
    w = fminf(fmaxf(w, 0.f), 1.f);
    a0 += s0[r] * w;
    a1 += s1[r] * w;
  }
  P[d0 * NG_ + g] = a0;
  P[(d0 + 1) * NG_ + g] = a1;
}

// ---------------- Kernel 1b: GNN, lane=node, xs & A register-resident ----------------
__global__ __launch_bounds__(256) void k_gnn(
    const float* __restrict__ embed, const float* __restrict__ gW,
    const float* __restrict__ gb, const int* __restrict__ fp,
    const float* __restrict__ adj, float* __restrict__ compound)
{
  const int d = blockIdx.x;
  const int tid = threadIdx.x;
  const int wid = tid >> 6, lane = tid & 63;
  __shared__ __align__(16) float WT[D_ * 52];
  __shared__ __align__(16) float hsl[NA_ * 52];
  __shared__ float xsl[NA_ * 53];
  __shared__ float bl[D_];
  __shared__ int fps[NA_];

  if (tid < NA_) fps[tid] = fp[d * NA_ + tid];
  if (wid == 0) { hsl[lane * 52 + 50] = 0.f; hsl[lane * 52 + 51] = 0.f; }
  __syncthreads();

  float xs[52];
  const float* erow = embed + (size_t)fps[lane] * D_;
#pragma unroll
  for (int j = 0; j < D_; ++j) xs[j] = erow[j];
  xs[50] = 0.f; xs[51] = 0.f;
  float Ar[NA_];
  const float* arow = adj + (size_t)d * NA_ * NA_ + lane * NA_;
#pragma unroll
  for (int j = 0; j < NA_; ++j) Ar[j] = arow[j];

  const int e0 = (wid < 2) ? wid * 13 : 26 + (wid - 2) * 12;
  const int ecnt = (wid < 2) ? 13 : 12;

  for (int layer = 0; layer < LG_; ++layer) {
    const float* Wg = gW + layer * D_ * D_;
    for (int i = tid; i < D_ * 52; i += 256) {
      int e = i / 52, dd = i - e * 52;
      WT[i] = (dd < D_) ? Wg[dd * D_ + e] : 0.f;
    }
    if (tid < D_) bl[tid] = gb[layer * D_ + tid];
    __syncthreads();

    for (int ei = 0; ei < ecnt; ++ei) {
      int e = e0 + ei;
      float c0 = bl[e], c1 = 0.f, c2 = 0.f, c3 = 0.f;
#pragma unroll
      for (int c = 0; c < 13; ++c) {
        float4 wv = *(const float4*)&WT[e * 52 + 4 * c];
        c0 += xs[4 * c + 0] * wv.x;
        c1 += xs[4 * c + 1] * wv.y;
        c2 += xs[4 * c + 2] * wv.z;
        c3 += xs[4 * c + 3] * wv.w;
      }
      hsl[lane * 52 + e] = fmaxf((c0 + c1) + (c2 + c3), 0.f);
    }
    __syncthreads();

    for (int c = wid; c < 13; c += 4) {
      float a0 = 0.f, a1 = 0.f, a2 = 0.f, a3 = 0.f;
#pragma unroll
      for (int m = 0; m < NA_; ++m) {
        float4 hv = *(const float4*)&hsl[m * 52 + 4 * c];
        float am = Ar[m];
        a0 += am * hv.x; a1 += am * hv.y; a2 += am * hv.z; a3 += am * hv.w;
      }
      int dd = 4 * c;
      xsl[lane * 53 + dd + 0] = xs[dd + 0] + a0;
      xsl[lane * 53 + dd + 1] = xs[dd + 1] + a1;
      if (dd + 2 < D_) {
        xsl[lane * 53 + dd + 2] = xs[dd + 2] + a2;
        xsl[lane * 53 + dd + 3] = xs[dd + 3] + a3;
      }
    }
    __syncthreads();
#pragma unroll
    for (int j = 0; j < D_; ++j) xs[j] = xsl[lane * 53 + j];
    __syncthreads();
  }

  if (wid == 0 && lane < D_) {
    float s = 0.f;
    for (int n = 0; n < NA_; ++n) s += xsl[n * 53 + lane];
    compound[d * D_ + lane] = s * (1.f / NA_);
  }
}

// ---------------- Kernel 2: com (register-direct) + comg store + conv1 stats ----------------
__global__ __launch_bounds__(384, 4) void k_conv1(
    const float* __restrict__ rma, const float* __restrict__ varr,
    const int* __restrict__ did, const float* __restrict__ P,
    const float* __restrict__ w1g, const float* __restrict__ b1g,
    float* __restrict__ comg, float* __restrict__ part1)
{
  const int b = blockIdx.x, tid = threadIdx.x;
  const int wid = tid >> 6;
  __shared__ float red[6][C1_ * 2];
  const int dd = did[b];
  const float* rb = rma  + (size_t)b * NG_ + 4 * tid;
  const float* vb = varr + (size_t)b * NG_ + 4 * tid;
  const float* pp = P    + (size_t)dd * NG_ + 4 * tid;

  float s1[C1_], s2[C1_];
#pragma unroll
  for (int c = 0; c < C1_; ++c) { s1[c] = 0.f; s2[c] = 0.f; }

  if (tid < 357) {
    float4 r0 = *(const float4*)(rb + 0),  r1 = *(const float4*)(rb + 4);
    float4 r2 = *(const float4*)(rb + 8),  r3 = *(const float4*)(rb + 12);
    float4 v0 = *(const float4*)(vb + 0),  v1 = *(const float4*)(vb + 4);
    float4 v2 = *(const float4*)(vb + 8),  v3 = *(const float4*)(vb + 12);
    float4 p0 = *(const float4*)(pp + 0),  p1 = *(const float4*)(pp + 4);
    float4 p2 = *(const float4*)(pp + 8),  p3 = *(const float4*)(pp + 12);
    const bool two = (tid < 356);
    float wE[9], wO[8];
    wE[0] = r0.x + p0.x * v0.x;  wO[0] = r0.y + p0.y * v0.y;
    wE[1] = r0.z + p0.z * v0.z;  wO[1] = r0.w + p0.w * v0.w;
    wE[2] = r1.x + p1.x * v1.x;  wO[2] = r1.y + p1.y * v1.y;
    wE[3] = r1.z + p1.z * v1.z;  wO[3] = r1.w + p1.w * v1.w;
    wE[4] = r2.x + p2.x * v2.x;  wO[4] = r2.y + p2.y * v2.y;
    wE[5] = r2.z + p2.z * v2.z;  wO[5] = r2.w + p2.w * v2.w;
    wE[6] = r3.x + p3.x * v3.x;  wO[6] = r3.y + p3.y * v3.y;
    wE[7] = r3.z + p3.z * v3.z;  wO[7] = r3.w + p3.w * v3.w;
    wE[8] = two ? (rb[16] + pp[16] * vb[16]) : 0.f;
    *(float4*)&comg[(size_t)b * NG_ + 4 * tid] =
        make_float4(wE[0], wO[0], wE[1], wO[1]);
#pragma unroll
    for (int c = 0; c < C1_; ++c) {
      float a0 = b1g[c], a1 = a0;
#pragma unroll
      for (int m = 0; m < 8; ++m) {
        float w = w1g[c * K1_ + 2 * m];
        a0 += w * wE[m]; a1 += w * wE[m + 1];
      }
#pragma unroll
      for (int m = 0; m < 7; ++m) {
        float w = w1g[c * K1_ + 2 * m + 1];
        a0 += w * wO[m]; a1 += w * wO[m + 1];
      }
      s1[c] = a0; s2[c] = a0 * a0;
      if (two) { s1[c] += a1; s2[c] += a1 * a1; }
    }
  } else if (tid < 360) {
    float4 r0 = *(const float4*)(rb);
    float4 v0 = *(const float4*)(vb);
    float4 p0 = *(const float4*)(pp);
    *(float4*)&comg[(size_t)b * NG_ + 4 * tid] =
        make_float4(r0.x + p0.x * v0.x, r0.y + p0.y * v0.y,
                    r0.z + p0.z * v0.z, r0.w + p0.w * v0.w);
  }

#pragma unroll
  for (int c = 0; c < C1_; ++c) {
#pragma unroll
    for (int off = 32; off > 0; off >>= 1) {
      s1[c] += __shfl_down(s1[c], off, 64);
      s2[c] += __shfl_down(s2[c], off, 64);
    }
  }
  if ((tid & 63) == 0) {
#pragma unroll
    for (int c = 0; c < C1_; ++c) {
      red[wid][c * 2 + 0] = s1[c];
      red[wid][c * 2 + 1] = s2[c];
    }
  }
  __syncthreads();
  if (tid < C1_ * 2) {
    float S = 0.f;
#pragma unroll
    for (int w = 0; w < 6; ++w) S += red[w][tid];
    part1[b * (C1_ * 2) + tid] = S;   // (b*C1 + c)*2 + s
  }
}

// ---------------- BN finalize (still used for bn1/bn2) ----------------
__global__ __launch_bounds__(256) void k_bnfin(
    const float* __restrict__ part, int nblk, int C, float N,
    const float* __restrict__ g, const float* __restrict__ bta,
    float* __restrict__ ac)
{
  const int c = blockIdx.x, tid = threadIdx.x;
  float s1 = 0.f, s2 = 0.f;
  for (int j = tid; j < nblk; j += 256) {
    s1 += part[(j * C + c) * 2 + 0];
    s2 += part[(j * C + c) * 2 + 1];
  }
#pragma unroll
  for (int off = 32; off > 0; off >>= 1) {
    s1 += __shfl_down(s1, off, 64);
    s2 += __shfl_down(s2, off, 64);
  }
  __shared__ float r1[4], r2[4];
  int w = tid >> 6;
  if ((tid & 63) == 0) { r1[w] = s1; r2[w] = s2; }
  __syncthreads();
  if (tid == 0) {
    float S1 = r1[0] + r1[1] + r1[2] + r1[3];
    float S2 = r2[0] + r2[1] + r2[2] + r2[3];
    float mean = S1 / N;
    float v = S2 / N - mean * mean;
    float a = g[c] * rsqrtf(v + EPS);
    ac[c] = a;
    ac[C + c] = bta[c] - mean * a;
  }
}

// ---------------- Kernel 4: channel-split half-LDS double-pass + float2 phase-B reads ----------------
__global__ __launch_bounds__(192, 6) void k_conv2(
    const float* __restrict__ comg, const float* __restrict__ w1g,
    const float* __restrict__ b1g, const float* __restrict__ ac1,
    const float* __restrict__ w2g, const float* __restrict__ b2g,
    float* __restrict__ x2g, float* __restrict__ part2)
{
  const int b = blockIdx.x, tid = threadIdx.x;
  const int wid = tid >> 6;                 // 0..2
  __shared__ __align__(8) float x1E[5 * X1ST_], x1O[5 * X1ST_];
  __shared__ float red[3][C2_ * 2];

  float A0[C2_], A1[C2_];
#pragma unroll
  for (int co = 0; co < C2_; ++co) { A0[co] = 0.f; A1[co] = 0.f; }

#pragma unroll 1
  for (int g = 0; g < 2; ++g) {
    if (g) __syncthreads();
#pragma unroll 1
    for (int j = tid; j < 357; j += 192) {
      const float* base = comg + (size_t)b * NG_ + 4 * j;
      float4 v0 = *(const float4*)(base + 0);
      float4 v1 = *(const float4*)(base + 4);
      float4 v2 = *(const float4*)(base + 8);
      float4 v3 = *(const float4*)(base + 12);
      const bool two = (j < 356);
      float wE[9], wO[8];
      wE[0] = v0.x; wE[1] = v0.z; wE[2] = v1.x; wE[3] = v1.z;
      wE[4] = v2.x; wE[5] = v2.z; wE[6] = v3.x; wE[7] = v3.z;
      wE[8] = two ? base[16] : 0.f;
      wO[0] = v0.y; wO[1] = v0.w; wO[2] = v1.y; wO[3] = v1.w;
      wO[4] = v2.y; wO[5] = v2.w; wO[6] = v3.y; wO[7] = v3.w;
#pragma unroll 1
      for (int cl = 0; cl < 5; ++cl) {
        const int c = g * 5 + cl;
        float a0 = b1g[c], a1 = a0;
#pragma unroll
        for (int m = 0; m < 8; ++m) {
          float w = w1g[c * K1_ + 2 * m];
          a0 += w * wE[m]; a1 += w * wE[m + 1];
        }
#pragma unroll
        for (int m = 0; m < 7; ++m) {
          float w = w1g[c * K1_ + 2 * m + 1];
          a0 += w * wO[m]; a1 += w * wO[m + 1];
        }
        float sc = ac1[c], sh = ac1[C1_ + c];
        x1E[cl * X1ST_ + j] = fmaxf(sc * a0 + sh, 0.f);
        if (two) x1O[cl * X1ST_ + j] = fmaxf(sc * a1 + sh, 0.f);
      }
    }
    __syncthreads();

    if (tid < 175) {
#pragma unroll 1
      for (int cl = 0; cl < 5; ++cl) {
        const int ci = g * 5 + cl;
        float xE[9], xO[8];
        {
          const float* pE = &x1E[cl * X1ST_ + 2 * tid];
          float2 e0 = *(const float2*)(pE + 0);
          float2 e1 = *(const float2*)(pE + 2);
          float2 e2 = *(const float2*)(pE + 4);
          float2 e3 = *(const float2*)(pE + 6);
          xE[0] = e0.x; xE[1] = e0.y; xE[2] = e1.x; xE[3] = e1.y;
          xE[4] = e2.x; xE[5] = e2.y; xE[6] = e3.x; xE[7] = e3.y;
          xE[8] = pE[8];
          const float* pO = &x1O[cl * X1ST_ + 2 * tid];
          float2 o0 = *(const float2*)(pO + 0);
          float2 o1 = *(const float2*)(pO + 2);
          float2 o2 = *(const float2*)(pO + 4);
          float2 o3 = *(const float2*)(pO + 6);
          xO[0] = o0.x; xO[1] = o0.y; xO[2] = o1.x; xO[3] = o1.y;
          xO[4] = o2.x; xO[5] = o2.y; xO[6] = o3.x; xO[7] = o3.y;
        }
#pragma unroll
        for (int co = 0; co < C2_; ++co) {
#pragma unroll
          for (int m = 0; m < 8; ++m) {
            float w = w2g[(co * C1_ + ci) * K1_ + 2 * m];
            A0[co] += w * xE[m]; A1[co] += w * xE[m + 1];
          }
#pragma unroll
          for (int m = 0; m < 7; ++m) {
            float w = w2g[(co * C1_ + ci) * K1_ + 2 * m + 1];
            A0[co] += w * xO[m]; A1[co] += w * xO[m + 1];
          }
        }
      }
    }
  }

  float t1[C2_], t2[C2_];
#pragma unroll
  for (int co = 0; co < C2_; ++co) { t1[co] = 0.f; t2[co] = 0.f; }
  if (tid < 175) {
#pragma unroll
    for (int co = 0; co < C2_; ++co) {
      float o0 = A0[co] + b2g[co];
      float o1 = A1[co] + b2g[co];
      *(float2*)&x2g[b * (C2_ * L2_) + co * L2_ + 2 * tid] = make_float2(o0, o1);
      t1[co] = o0 + o1; t2[co] = o0 * o0 + o1 * o1;
    }
  }
#pragma unroll
  for (int co = 0; co < C2_; ++co) {
#pragma unroll
    for (int off = 32; off > 0; off >>= 1) {
      t1[co] += __shfl_down(t1[co], off, 64);
      t2[co] += __shfl_down(t2[co], off, 64);
    }
  }
  if ((tid & 63) == 0) {
#pragma unroll
    for (int co = 0; co < C2_; ++co) {
      red[wid][co * 2 + 0] = t1[co];
      red[wid][co * 2 + 1] = t2[co];
    }
  }
  __syncthreads();
  if (tid < C2_ * 2) {
    float S = red[0][tid] + red[1][tid] + red[2][tid];
    part2[b * (C2_ * 2) + tid] = S;   // (b*C2 + c)*2 + s
  }
}

// ---------------- Kernel 6: fused BN2+relu+maxpool5, lin_gene, concat, mlin + tanh, mconv1, stats ----------------
__global__ __launch_bounds__(256) void k_gene(
    const float* __restrict__ x2g, const float* __restrict__ ac2,
    const int* __restrict__ did, const float* __restrict__ compound,
    const float* __restrict__ lgwg, const float* __restrict__ lgbg,
    const float* __restrict__ mwg, const float* __restrict__ mbg,
    const float* __restrict__ mw1g, const float* __restrict__ mb1g,
    float* __restrict__ mraw1, float* __restrict__ partm1)
{
  const int b = blockIdx.x, tid = threadIdx.x;
  __shared__ float pooled[C2_ * LP_];
  __shared__ float lgw[LP_ * LO_];
  __shared__ float cat[CAT_];
  __shared__ float mv[M_];
  __shared__ float mvp[2][M_];
  __shared__ float red1[C2_ * LM1_], red2[C2_ * LM1_];
  __shared__ float a2s[C2_], c2s[C2_];
  if (tid < C2_) { a2s[tid] = ac2[tid]; c2s[tid] = ac2[C2_ + tid]; }
  for (int i = tid; i < LP_ * LO_; i += 256) lgw[i] = lgwg[i];
  __syncthreads();
  for (int i = tid; i < C2_ * LP_; i += 256) {
    int c = i / LP_, p = i - c * LP_;
    const float* xr = x2g + (size_t)b * (C2_ * L2_) + c * L2_ + 5 * p;
    float aa = a2s[c], cc = c2s[c];
    float m = aa * xr[0] + cc;
    m = fmaxf(m, aa * xr[1] + cc);
    m = fmaxf(m, aa * xr[2] + cc);
    m = fmaxf(m, aa * xr[3] + cc);
    m = fmaxf(m, aa * xr[4] + cc);
    pooled[i] = fmaxf(m, 0.f);
  }
  __syncthreads();
  if (tid < 160) {
    int c = tid >> 5, o = tid & 31;
    float a = lgbg[o];
    for (int l = 0; l < LP_; ++l) a += pooled[c * LP_ + l] * lgw[l * LO_ + o];
    cat[tid] = fmaxf(a, 0.f);
  } else if (tid < CAT_) {
    cat[tid] = compound[did[b] * D_ + (tid - 160)];
  }
  __syncthreads();
  if (tid < 200) {
    int half = tid / 100, o = tid - half * 100;
    float a = 0.f;
    int i0 = half * 105;
    for (int i = i0; i < i0 + 105; ++i) a += cat[i] * mwg[i * M_ + o];
    mvp[half][o] = a;
  }
  __syncthreads();
  if (tid < M_) mv[tid] = tanhf(mvp[0][tid] + mvp[1][tid] + mbg[tid]);
  __syncthreads();
  if (tid < C2_ * LM1_) {
    int c = tid / LM1_, t = tid - c * LM1_;
    float a = mb1g[c];
#pragma unroll
    for (int k = 0; k < 10; ++k) a += mw1g[c * 10 + k] * mv[2 * t + k];
    mraw1[b * (C2_ * LM1_) + c * LM1_ + t] = a;
    red1[tid] = a;
    red2[tid] = a * a;
  }
  __syncthreads();
  if (tid < C2_) {
    float S1 = 0.f, S2 = 0.f;
    for (int j = 0; j < LM1_; ++j) { S1 += red1[tid * LM1_ + j]; S2 += red2[tid * LM1_ + j]; }
    partm1[(b * C2_ + tid) * 2 + 0] = S1;
    partm1[(b * C2_ + tid) * 2 + 1] = S2;
  }
}

// ---------------- Kernel 8: FUSED bnfin_m1 + mbn1+maxpool3 + mconv2 + stats ----------------
// Each of the 16 blocks redundantly reduces partm1 (4096x10, fixed order ->
// deterministic & identical across blocks) and computes acm1 in LDS, saving
// a separate k_bnfin launch.
__global__ __launch_bounds__(256) void k_mhead2(
    const float* __restrict__ mraw1, const float* __restrict__ partm1,
    const float* __restrict__ mbn1g, const float* __restrict__ mbn1b,
    const float* __restrict__ mw2g, const float* __restrict__ mb2g,
    float* __restrict__ mraw2, float* __restrict__ partm2)
{
  const int tid = threadIdx.x;
  const int b = blockIdx.x * 256 + tid;
  const int wid = tid >> 6;
  __shared__ float w2[C2_ * C2_ * 10];
  __shared__ float a1[C2_], c1[C2_], b2s[C2_];
  __shared__ float rw1[C2_][4], rw2[C2_][4];

  // --- folded bnfin_m1 ---
  float l1[C2_], l2[C2_];
#pragma unroll
  for (int c = 0; c < C2_; ++c) { l1[c] = 0.f; l2[c] = 0.f; }
  for (int j = tid; j < B_; j += 256) {
    const float* pr = partm1 + j * (C2_ * 2);
#pragma unroll
    for (int c = 0; c < C2_; ++c) {
      l1[c] += pr[c * 2 + 0];
      l2[c] += pr[c * 2 + 1];
    }
  }
#pragma unroll
  for (int c = 0; c < C2_; ++c) {
#pragma unroll
    for (int off = 32; off > 0; off >>= 1) {
      l1[c] += __shfl_down(l1[c], off, 64);
      l2[c] += __shfl_down(l2[c], off, 64);
    }
  }
  if ((tid & 63) == 0) {
#pragma unroll
    for (int c = 0; c < C2_; ++c) { rw1[c][wid] = l1[c]; rw2[c][wid] = l2[c]; }
  }
  if (tid < C2_ * C2_ * 10) w2[tid] = mw2g[tid];
  __syncthreads();
  if (tid < C2_) {
    float S1 = rw1[tid][0] + rw1[tid][1] + rw1[tid][2] + rw1[tid][3];
    float S2 = rw2[tid][0] + rw2[tid][1] + rw2[tid][2] + rw2[tid][3];
    const float N = (float)B_ * (float)LM1_;
    float mean = S1 / N;
    float v = S2 / N - mean * mean;
    float a = mbn1g[tid] * rsqrtf(v + EPS);
    a1[tid] = a;
    c1[tid] = mbn1b[tid] - mean * a;
    b2s[tid] = mb2g[tid];
  }
  __syncthreads();

  // --- main body (unchanged) ---
  float p[C2_ * PM1_];
  const float* row = mraw1 + (size_t)b * (C2_ * LM1_);
#pragma unroll
  for (int c = 0; c < C2_; ++c) {
    float ac = a1[c], cc = c1[c];
#pragma unroll
    for (int q = 0; q < PM1_; ++q) {
      float m = ac * row[c * LM1_ + 3 * q] + cc;
      m = fmaxf(m, ac * row[c * LM1_ + 3 * q + 1] + cc);
      m = fmaxf(m, ac * row[c * LM1_ + 3 * q + 2] + cc);
      p[c * PM1_ + q] = m;
    }
  }
#pragma unroll
  for (int co = 0; co < C2_; ++co) {
    float t1 = 0.f, t2 = 0.f;
#pragma unroll
    for (int l = 0; l < LM2_; ++l) {
      float a = b2s[co];
#pragma unroll
      for (int ci = 0; ci < C2_; ++ci)
#pragma unroll
        for (int k = 0; k < 10; ++k)
          a += w2[(co * C2_ + ci) * 10 + k] * p[ci * PM1_ + 2 * l + k];
      mraw2[b * (C2_ * LM2_) + co * LM2_ + l] = a;
      t1 += a; t2 += a * a;
    }
#pragma unroll
    for (int off = 32; off > 0; off >>= 1) {
      t1 += __shfl_down(t1, off, 64);
      t2 += __shfl_down(t2, off, 64);
    }
    if ((tid & 63) == 0) { rw1[co][wid] = t1; rw2[co][wid] = t2; }
  }
  __syncthreads();
  if (tid < C2_ * 2) {
    int co = tid >> 1, s = tid & 1;
    float S = 0.f;
#pragma unroll
    for (int w = 0; w < 4; ++w) S += (s ? rw2[co][w] : rw1[co][w]);
    partm2[blockIdx.x * (C2_ * 2) + tid] = S;
  }
}

// ---------------- Kernel 10: FUSED bnfin_m2 + mbn2 + maxpool3 + output layer ----------------
// Each of the 16 blocks redundantly reduces the 160-float partm2 and computes
// acm2 in LDS, saving a separate k_bnfin launch.
__global__ __launch_bounds__(256) void k_final(
    const float* __restrict__ mraw2, const float* __restrict__ partm2,
    const float* __restrict__ mbn2g, const float* __restrict__ mbn2b,
    const float* __restrict__ owg, const float* __restrict__ obg,
    float* __restrict__ out)
{
  const int tid = threadIdx.x;
  const int b = blockIdx.x * 256 + tid;
  __shared__ float sred[C2_ * 2];
  __shared__ float a2[C2_], c2[C2_];
  if (tid < C2_ * 2) {
    float S = 0.f;
#pragma unroll
    for (int w = 0; w < 16; ++w) S += partm2[w * (C2_ * 2) + tid];
    sred[tid] = S;
  }
  __syncthreads();
  if (tid < C2_) {
    float S1 = sred[tid * 2 + 0];
    float S2 = sred[tid * 2 + 1];
    const float N = (float)B_ * (float)LM2_;
    float mean = S1 / N;
    float v = S2 / N - mean * mean;
    float a = mbn2g[tid] * rsqrtf(v + EPS);
    a2[tid] = a;
    c2[tid] = mbn2b[tid] - mean * a;
  }
  __syncthreads();

  float y = obg[0];
#pragma unroll
  for (int c = 0; c < C2_; ++c) {
    float a = a2[c], cc = c2[c];
    float m = a * mraw2[b * 15 + c * 3 + 0] + cc;
    m = fmaxf(m, a * mraw2[b * 15 + c * 3 + 1] + cc);
    m = fmaxf(m, a * mraw2[b * 15 + c * 3 + 2] + cc);
    y += owg[c] * m;
  }
  out[b] = y;
}

extern "C" void kernel_launch(void* const* d_in, const int* in_sizes, int n_in,
                              void* d_out, int out_size, void* d_ws, size_t ws_size,
                              hipStream_t stream) {
  (void)in_sizes; (void)n_in; (void)out_size; (void)ws_size;
  const float* rma   = (const float*)d_in[0];
  const float* varr  = (const float*)d_in[1];
  const int*   did   = (const int*)d_in[2];
  const float* fw    = (const float*)d_in[3];
  const float* sim   = (const float*)d_in[4];
  const float* embed = (const float*)d_in[5];
  const float* gW    = (const float*)d_in[6];
  const float* gb    = (const float*)d_in[7];
  const int*   fp    = (const int*)d_in[8];
  const float* adj   = (const float*)d_in[9];
  const float* w1g   = (const float*)d_in[10];
  const float* b1g   = (const float*)d_in[11];
  const float* bn1g  = (const float*)d_in[12];
  const float* bn1b  = (const float*)d_in[13];
  const float* w2g   = (const float*)d_in[14];
  const float* b2g   = (const float*)d_in[15];
  const float* bn2g  = (const float*)d_in[16];
  const float* bn2b  = (const float*)d_in[17];
  const float* lgwg  = (const float*)d_in[18];
  const float* lgbg  = (const float*)d_in[19];
  const float* mwg   = (const float*)d_in[20];
  const float* mbg   = (const float*)d_in[21];
  const float* mw1g  = (const float*)d_in[22];
  const float* mb1g  = (const float*)d_in[23];
  const float* mbn1g = (const float*)d_in[24];
  const float* mbn1b = (const float*)d_in[25];
  const float* mw2g  = (const float*)d_in[26];
  const float* mb2g  = (const float*)d_in[27];
  const float* mbn2g = (const float*)d_in[28];
  const float* mbn2b = (const float*)d_in[29];
  const float* owg   = (const float*)d_in[30];
  const float* obg   = (const float*)d_in[31];
  float* out = (float*)d_out;

  float* ws = (float*)d_ws;
  size_t o = 0;
  float* P        = ws + o; o += (size_t)DR_ * NG_;
  float* compound = ws + o; o += (size_t)DR_ * D_;
  float* comg     = ws + o; o += (size_t)B_ * NG_;
  float* part1    = ws + o; o += (size_t)B_ * C1_ * 2;
  float* ac1      = ws + o; o += 2 * C1_;
  float* x2g      = ws + o; o += (size_t)B_ * C2_ * L2_;
  float* part2    = ws + o; o += (size_t)B_ * C2_ * 2;
  float* ac2      = ws + o; o += 2 * C2_;
  float* mraw1    = ws + o; o += (size_t)B_ * C2_ * LM1_;
  float* partm1   = ws + o; o += (size_t)B_ * C2_ * 2;
  float* mraw2    = ws + o; o += (size_t)B_ * C2_ * LM2_;
  float* partm2   = ws + o; o += 16 * C2_ * 2;

  hipLaunchKernelGGL(k_fuse, dim3(DR_ / 2, 6), dim3(256), 0, stream, fw, sim, P);
  hipLaunchKernelGGL(k_gnn, dim3(DR_), dim3(256), 0, stream,
                     embed, gW, gb, fp, adj, compound);
  hipLaunchKernelGGL(k_conv1, dim3(B_), dim3(384), 0, stream,
                     rma, varr, did, P, w1g, b1g, comg, part1);
  hipLaunchKernelGGL(k_bnfin, dim3(C1_), dim3(256), 0, stream,
                     part1, B_, C1_, (float)B_ * (float)L1_, bn1g, bn1b, ac1);
  hipLaunchKernelGGL(k_conv2, dim3(B_), dim3(192), 0, stream,
                     comg, w1g, b1g, ac1, w2g, b2g, x2g, part2);
  hipLaunchKernelGGL(k_bnfin, dim3(C2_), dim3(256), 0, stream,
                     part2, B_, C2_, (float)B_ * (float)L2_, bn2g, bn2b, ac2);
  hipLaunchKernelGGL(k_gene, dim3(B_), dim3(256), 0, stream,
                     x2g, ac2, did, compound, lgwg, lgbg, mwg, mbg, mw1g, mb1g,
                     mraw1, partm1);
  hipLaunchKernelGGL(k_mhead2, dim3(16), dim3(256), 0, stream,
                     mraw1, partm1, mbn1g, mbn1b, mw2g, mb2g, mraw2, partm2);
  hipLaunchKernelGGL(k_final, dim3(16), dim3(256), 0, stream,
                     mraw2, partm2, mbn2g, mbn2b, owg, obg, out);
}